// Round 10
// baseline (662.427 us; speedup 1.0000x reference)
//
#include <hip/hip_runtime.h>
#include <hip/hip_fp16.h>

#define WG 256

// ---- fp16 helpers ----
__device__ __forceinline__ void fma8(float* a, uint4 u, float w) {
    union { unsigned int x; __half2 h; } c;
    float2 v;
    c.x = u.x; v = __half22float2(c.h); a[0] += w * v.x; a[1] += w * v.y;
    c.x = u.y; v = __half22float2(c.h); a[2] += w * v.x; a[3] += w * v.y;
    c.x = u.z; v = __half22float2(c.h); a[4] += w * v.x; a[5] += w * v.y;
    c.x = u.w; v = __half22float2(c.h); a[6] += w * v.x; a[7] += w * v.y;
}
__device__ __forceinline__ uint4 f8_to_h8(const float* f) {
    union { unsigned int x; __half2 h; } a0, a1, a2, a3;
    a0.h = __floats2half2_rn(f[0], f[1]);
    a1.h = __floats2half2_rn(f[2], f[3]);
    a2.h = __floats2half2_rn(f[4], f[5]);
    a3.h = __floats2half2_rn(f[6], f[7]);
    return make_uint4(a0.x, a1.x, a2.x, a3.x);
}
__device__ __forceinline__ uint2 f4_to_h4(float4 v) {
    union { unsigned int x; __half2 h; } a, b;
    a.h = __floats2half2_rn(v.x, v.y);
    b.h = __floats2half2_rn(v.z, v.w);
    return make_uint2(a.x, b.x);
}

// ---------------- setup kernels ----------------

__global__ void k_zero2(int* __restrict__ a, int* __restrict__ b, int n) {
    int i = blockIdx.x * blockDim.x + threadIdx.x;
    if (i < n) { a[i] = 0; b[i] = 0; }
}

__global__ void k_count(const int* __restrict__ dst, int* __restrict__ deg, int E) {
    int e = blockIdx.x * blockDim.x + threadIdx.x;
    if (e < E) atomicAdd(&deg[dst[e]], 1);
}

__global__ void k_dis(const int* __restrict__ deg, float* __restrict__ dis, int N) {
    int n = blockIdx.x * blockDim.x + threadIdx.x;
    if (n < N) {
        int d = deg[n];
        dis[n] = (d > 0) ? rsqrtf((float)d) : 0.0f;
    }
}

// ---- hierarchical scan ----
__global__ __launch_bounds__(1024) void k_scan_blk(const int* __restrict__ deg,
                                                   int* __restrict__ rowptr,
                                                   int* __restrict__ bsum, int N) {
    __shared__ int s[1024];
    int t = threadIdx.x;
    int gid = blockIdx.x * 1024 + t;
    int v = (gid < N) ? deg[gid] : 0;
    s[t] = v;
    __syncthreads();
    for (int off = 1; off < 1024; off <<= 1) {
        int u = (t >= off) ? s[t - off] : 0;
        __syncthreads();
        s[t] += u;
        __syncthreads();
    }
    if (gid < N) rowptr[gid] = s[t] - v;
    if (t == 1023) bsum[blockIdx.x] = s[1023];
}

__global__ void k_scan_top(int* __restrict__ bsum, int* __restrict__ rowptr_last, int nb) {
    if (threadIdx.x == 0 && blockIdx.x == 0) {
        int run = 0;
        for (int i = 0; i < nb; ++i) { int v = bsum[i]; bsum[i] = run; run += v; }
        *rowptr_last = run;
    }
}

__global__ void k_scan_add(int* __restrict__ rowptr, const int* __restrict__ bsum, int N) {
    int gid = blockIdx.x * blockDim.x + threadIdx.x;
    if (gid < N) rowptr[gid] += bsum[gid >> 10];
}

__global__ void k_scatter(const int* __restrict__ src, const int* __restrict__ dst,
                          const int* __restrict__ rowptr, int* __restrict__ fill,
                          const float* __restrict__ dis,
                          int2* __restrict__ emeta, int E) {
    int e = blockIdx.x * blockDim.x + threadIdx.x;
    if (e >= E) return;
    int d = dst[e], s = src[e];
    int slot = rowptr[d] + atomicAdd(&fill[d], 1);
    emeta[slot] = make_int2(s, __float_as_int(dis[s] * dis[d]));
}

// X (B,WIN,N) f32 -> h0 [n][w][b] f32
__global__ void k_xpose(const float* __restrict__ X, float* __restrict__ h0, int N) {
    long long tid = (long long)blockIdx.x * blockDim.x + threadIdx.x;
    if (tid >= (long long)N * 20) return;
    int n = (int)(tid / 20), r = (int)(tid % 20);
    int b = r & 3, w = r >> 2;
    h0[tid] = X[(size_t)(b * 5 + w) * N + n];
}

// ---------------- layer-0 propagation (f32, table L2-resident) ----------------
__global__ void k_spmm20(const int* __restrict__ rowptr, const int2* __restrict__ emeta,
                         const float* __restrict__ hin, float* __restrict__ hout, int N) {
    long long tid = (long long)blockIdx.x * blockDim.x + threadIdx.x;
    if (tid >= (long long)N * 5) return;
    int n = (int)(tid / 5), w = (int)(tid % 5);
    const float4* hin4 = (const float4*)hin;
    float ax = 0.f, ay = 0.f, az = 0.f, aw = 0.f;
    float bx = 0.f, by = 0.f, bz = 0.f, bw = 0.f;
    int j = rowptr[n], j1 = rowptr[n + 1];
    for (; j + 1 < j1; j += 2) {
        int2 m0 = emeta[j], m1 = emeta[j + 1];
        float4 g0 = hin4[(size_t)m0.x * 5 + w];
        float4 g1 = hin4[(size_t)m1.x * 5 + w];
        float w0 = __int_as_float(m0.y), w1 = __int_as_float(m1.y);
        ax += w0 * g0.x; ay += w0 * g0.y; az += w0 * g0.z; aw += w0 * g0.w;
        bx += w1 * g1.x; by += w1 * g1.y; bz += w1 * g1.z; bw += w1 * g1.w;
    }
    if (j < j1) {
        int2 m = emeta[j];
        float4 g = hin4[(size_t)m.x * 5 + w];
        float wt = __int_as_float(m.y);
        ax += wt * g.x; ay += wt * g.y; az += wt * g.z; aw += wt * g.w;
    }
    float4 o; o.x = ax + bx; o.y = ay + by; o.z = az + bz; o.w = aw + bw;
    ((float4*)hout)[(size_t)n * 5 + w] = o;
}

// acc[n][b][o] (+)= sum_w h[n][w][b] * W[w][o]
__global__ void k_mm5(const float* __restrict__ h, const float* __restrict__ W,
                      float* __restrict__ acc, int N, int first) {
    __shared__ float w[5 * 32];
    int t = threadIdx.x;
    if (t < 160) w[t] = W[t];
    __syncthreads();
    long long tid = (long long)blockIdx.x * WG + t;
    int node = (int)(tid >> 7);
    if (node >= N) return;
    int b = ((int)tid >> 5) & 3, o = (int)tid & 31;
    const float* hp = h + (size_t)node * 20 + b;
    float a = first ? 0.0f : acc[tid];
#pragma unroll
    for (int f = 0; f < 5; ++f) a += hp[f * 4] * w[f * 32 + o];
    acc[tid] = a;
}

// layer-0 tail: acc += h20*W0[3]; v=tanh(acc+b0); hout(fp16)=v; acc_out = v*Wnext[k=0]
// 8 nodes per 256-thread block (32 lanes/node) -> grid = (N+7)/8
__global__ __launch_bounds__(256) void k_mm5_final(const float* __restrict__ h20,
                                                   const float* __restrict__ W03,
                                                   const float* __restrict__ bias,
                                                   const float* __restrict__ acc_in,
                                                   uint2* __restrict__ hout,
                                                   const float* __restrict__ Wnext,
                                                   float* __restrict__ acc_out, int N) {
    __shared__ float4 wn4[256];
    __shared__ float4 w03[40];
    __shared__ float  hs[8 * 132];
    int t = threadIdx.x;
    wn4[t] = ((const float4*)Wnext)[t];
    if (t < 40) w03[t] = ((const float4*)W03)[t];
    __syncthreads();
    int nl = t >> 5, lane = t & 31, b = lane >> 3, q = lane & 7;
    int n = blockIdx.x * 8 + nl;
    bool valid = (n < N);
    float4 v4 = make_float4(0.f, 0.f, 0.f, 0.f);
    if (valid) {
        float4 a = ((const float4*)acc_in)[(size_t)n * 32 + lane];
#pragma unroll
        for (int w = 0; w < 5; ++w) {
            float hv = h20[(size_t)n * 20 + w * 4 + b];
            float4 wv = w03[w * 8 + q];
            a.x += hv * wv.x; a.y += hv * wv.y; a.z += hv * wv.z; a.w += hv * wv.w;
        }
        float4 b4 = ((const float4*)bias)[q];
        v4.x = tanhf(a.x + b4.x); v4.y = tanhf(a.y + b4.y);
        v4.z = tanhf(a.z + b4.z); v4.w = tanhf(a.w + b4.w);
        hout[(size_t)n * 32 + lane] = f4_to_h4(v4);
    }
    float* hrow = &hs[nl * 132 + b * 33 + q * 4];
    hrow[0] = v4.x; hrow[1] = v4.y; hrow[2] = v4.z; hrow[3] = v4.w;
    __syncthreads();
    float sx = 0.f, sy = 0.f, sz = 0.f, sw = 0.f;
    const float* hb = &hs[nl * 132 + b * 33];
#pragma unroll
    for (int f = 0; f < 32; ++f) {
        float hv = hb[f];
        float4 wv = wn4[f * 8 + q];
        sx += hv * wv.x; sy += hv * wv.y; sz += hv * wv.z; sw += hv * wv.w;
    }
    if (valid) {
        float4 o; o.x = sx; o.y = sy; o.z = sz; o.w = sw;
        ((float4*)acc_out)[(size_t)n * 32 + lane] = o;
    }
}

// ================= fused hops, 16 lanes/node, uint4 gathers, UNROLL-2 =================
// thread t: node_l = t>>4 (16 nodes/block), l = t&15; b = l>>2, og = l&3
// hs: [nb][36] stride (16B-aligned, <=2-way banks).
// VGPR history: unroll-4 uint4 -> 156 VGPR -> 2 waves/SIMD -> 132us (round 9, SLOWER).
// unroll-2 targets <=128 VGPR (the m69 occupancy step) with same in-flight bytes
// as round 5 (2x16B vs 4x8B) but half the load instructions.

#define GATHER_BODY                                                              \
    float a[8] = {0.f,0.f,0.f,0.f,0.f,0.f,0.f,0.f};                             \
    if (valid) {                                                                 \
        int j = rowptr[n], j1 = rowptr[n + 1];                                   \
        for (; j + 1 < j1; j += 2) {                                             \
            int2 m0 = emeta[j], m1 = emeta[j + 1];                               \
            uint4 u0 = hin[(size_t)m0.x * 16 + l];                               \
            uint4 u1 = hin[(size_t)m1.x * 16 + l];                               \
            fma8(a, u0, __int_as_float(m0.y));                                   \
            fma8(a, u1, __int_as_float(m1.y));                                   \
        }                                                                        \
        if (j < j1) {                                                            \
            int2 m = emeta[j];                                                   \
            uint4 u = hin[(size_t)m.x * 16 + l];                                 \
            fma8(a, u, __int_as_float(m.y));                                     \
        }                                                                        \
    }

// mid hop: hnext = A*hin (fp16); acc += hnext * Wk
__global__ __launch_bounds__(256) void k_hop_fused(const int* __restrict__ rowptr,
                                                   const int2* __restrict__ emeta,
                                                   const uint4* __restrict__ hin,
                                                   uint4* __restrict__ hnext,
                                                   const float* __restrict__ Wk,
                                                   float* __restrict__ acc, int N) {
    __shared__ float4 ws4[256];
    __shared__ float  hs[64 * 36];

    int t = threadIdx.x;
    ws4[t] = ((const float4*)Wk)[t];

    int node_l = t >> 4, l = t & 15;
    int n = blockIdx.x * 16 + node_l;
    bool valid = (n < N);
    int b = l >> 2, og = l & 3;
    int nb = node_l * 4 + b;

    GATHER_BODY
    if (valid) hnext[(size_t)n * 16 + l] = f8_to_h8(a);

    float* hrow = &hs[nb * 36 + og * 8];
#pragma unroll
    for (int i = 0; i < 8; ++i) hrow[i] = a[i];
    __syncthreads();
    if (!valid) return;

    float s[8] = {0.f,0.f,0.f,0.f,0.f,0.f,0.f,0.f};
    const float* hb = &hs[nb * 36];
#pragma unroll
    for (int f = 0; f < 32; ++f) {
        float hv = hb[f];
        float4 w0 = ws4[f * 8 + og * 2];
        float4 w1 = ws4[f * 8 + og * 2 + 1];
        s[0] += hv * w0.x; s[1] += hv * w0.y; s[2] += hv * w0.z; s[3] += hv * w0.w;
        s[4] += hv * w1.x; s[5] += hv * w1.y; s[6] += hv * w1.z; s[7] += hv * w1.w;
    }
    float4* ap = (float4*)acc + ((size_t)n * 4 + b) * 8 + og * 2;
    float4 c0 = ap[0], c1 = ap[1];
    c0.x += s[0]; c0.y += s[1]; c0.z += s[2]; c0.w += s[3];
    c1.x += s[4]; c1.y += s[5]; c1.z += s[6]; c1.w += s[7];
    ap[0] = c0; ap[1] = c1;
}

// last hop of a layer:
// MODE 1: v=tanh(acc+h'*Wk+b); hout(fp16)=v; acc_out = v*Wnext (next layer k=0)
// MODE 2: v=tanh(acc+h'*Wk+b); out_h(f32)=v; pred = v.Wr + br
template <int MODE>
__global__ __launch_bounds__(256) void k_hop_last(const int* __restrict__ rowptr,
                                                  const int2* __restrict__ emeta,
                                                  const uint4* __restrict__ hin,
                                                  const float* __restrict__ Wk,
                                                  const float* __restrict__ acc_in,
                                                  const float* __restrict__ bias,
                                                  uint4* __restrict__ hout,
                                                  const float* __restrict__ Wnext,
                                                  float* __restrict__ acc_out,
                                                  float* __restrict__ out_h,
                                                  const float* __restrict__ Wr,
                                                  const float* __restrict__ br,
                                                  float* __restrict__ pred, int N) {
    __shared__ float4 ws4[256];
    __shared__ float4 wn4[MODE == 1 ? 256 : 1];
    __shared__ float  hs[64 * 36];

    int t = threadIdx.x;
    ws4[t] = ((const float4*)Wk)[t];
    if (MODE == 1) wn4[t] = ((const float4*)Wnext)[t];

    int node_l = t >> 4, l = t & 15;
    int n = blockIdx.x * 16 + node_l;
    bool valid = (n < N);
    int b = l >> 2, og = l & 3;
    int nb = node_l * 4 + b;

    GATHER_BODY

    float* hrow = &hs[nb * 36 + og * 8];
#pragma unroll
    for (int i = 0; i < 8; ++i) hrow[i] = a[i];
    __syncthreads();

    float s[8] = {0.f,0.f,0.f,0.f,0.f,0.f,0.f,0.f};
    const float* hb = &hs[nb * 36];
#pragma unroll
    for (int f = 0; f < 32; ++f) {
        float hv = hb[f];
        float4 w0 = ws4[f * 8 + og * 2];
        float4 w1 = ws4[f * 8 + og * 2 + 1];
        s[0] += hv * w0.x; s[1] += hv * w0.y; s[2] += hv * w0.z; s[3] += hv * w0.w;
        s[4] += hv * w1.x; s[5] += hv * w1.y; s[6] += hv * w1.z; s[7] += hv * w1.w;
    }

    float v[8];
    if (valid) {
        const float4* ai = (const float4*)acc_in + ((size_t)n * 4 + b) * 8 + og * 2;
        float4 c0 = ai[0], c1 = ai[1];
        float4 b0 = ((const float4*)bias)[og * 2];
        float4 b1 = ((const float4*)bias)[og * 2 + 1];
        v[0] = tanhf(c0.x + s[0] + b0.x); v[1] = tanhf(c0.y + s[1] + b0.y);
        v[2] = tanhf(c0.z + s[2] + b0.z); v[3] = tanhf(c0.w + s[3] + b0.w);
        v[4] = tanhf(c1.x + s[4] + b1.x); v[5] = tanhf(c1.y + s[5] + b1.y);
        v[6] = tanhf(c1.z + s[6] + b1.z); v[7] = tanhf(c1.w + s[7] + b1.w);
    } else {
#pragma unroll
        for (int i = 0; i < 8; ++i) v[i] = 0.f;
    }

    if (MODE == 1) {
        if (valid) hout[(size_t)n * 16 + l] = f8_to_h8(v);
        __syncthreads();           // all reads of hs (h') complete
#pragma unroll
        for (int i = 0; i < 8; ++i) hrow[i] = v[i];
        __syncthreads();
        float r[8] = {0.f,0.f,0.f,0.f,0.f,0.f,0.f,0.f};
#pragma unroll
        for (int f = 0; f < 32; ++f) {
            float hv = hb[f];
            float4 w0 = wn4[f * 8 + og * 2];
            float4 w1 = wn4[f * 8 + og * 2 + 1];
            r[0] += hv * w0.x; r[1] += hv * w0.y; r[2] += hv * w0.z; r[3] += hv * w0.w;
            r[4] += hv * w1.x; r[5] += hv * w1.y; r[6] += hv * w1.z; r[7] += hv * w1.w;
        }
        if (valid) {
            float4* ao = (float4*)acc_out + ((size_t)n * 4 + b) * 8 + og * 2;
            ao[0] = make_float4(r[0], r[1], r[2], r[3]);
            ao[1] = make_float4(r[4], r[5], r[6], r[7]);
        }
    } else {
        if (valid) {
            float4* oh = (float4*)out_h + ((size_t)b * N + n) * 8 + og * 2;
            oh[0] = make_float4(v[0], v[1], v[2], v[3]);
            oh[1] = make_float4(v[4], v[5], v[6], v[7]);
            float4 wr0 = ((const float4*)Wr)[og * 2];
            float4 wr1 = ((const float4*)Wr)[og * 2 + 1];
            float p = v[0]*wr0.x + v[1]*wr0.y + v[2]*wr0.z + v[3]*wr0.w
                    + v[4]*wr1.x + v[5]*wr1.y + v[6]*wr1.z + v[7]*wr1.w;
            p += __shfl_xor(p, 1);
            p += __shfl_xor(p, 2);
            if (og == 0) pred[(size_t)b * N + n] = p + br[0];
        }
    }
}

// ---------------- driver ----------------

extern "C" void kernel_launch(void* const* d_in, const int* in_sizes, int n_in,
                              void* d_out, int out_size, void* d_ws, size_t ws_size,
                              hipStream_t stream) {
    const float* X  = (const float*)d_in[0];
    const int*   ei = (const int*)d_in[1];
    const float* W0 = (const float*)d_in[2];
    const float* b0 = (const float*)d_in[3];
    const float* W1 = (const float*)d_in[4];
    const float* b1 = (const float*)d_in[5];
    const float* W2 = (const float*)d_in[6];
    const float* b2 = (const float*)d_in[7];
    const float* Wr = (const float*)d_in[8];
    const float* br = (const float*)d_in[9];

    const int N = in_sizes[0] / 20;
    const int E = in_sizes[1] / 2;
    const int* src = ei;
    const int* dst = ei + E;
    const int nscan = (N + 1023) / 1024;

    char* ws = (char*)d_ws;
    size_t off = 0;
    auto take = [&](size_t bytes) -> char* {
        char* p = ws + off;
        off = (off + bytes + 255) & ~(size_t)255;
        return p;
    };
    int*   deg    = (int*)  take((size_t)N * 4);
    int*   fill   = (int*)  take((size_t)N * 4);
    int*   rowptr = (int*)  take(((size_t)N + 1) * 4);
    float* dis    = (float*)take((size_t)N * 4);
    int*   bsum   = (int*)  take((size_t)(nscan + 1) * 4);
    int2*  emeta  = (int2*) take((size_t)E * 8);
    float* acc    = (float*)take((size_t)N * 128 * 4);
    void*  h16a   = (void*) take((size_t)N * 128 * 2);   // fp16 node features
    void*  h16b   = (void*) take((size_t)N * 128 * 2);
    float* h20a   = (float*)take((size_t)N * 20 * 4);    // layer-0 f32 ping-pong
    float* h20b   = (float*)take((size_t)N * 20 * 4);
    if (ws_size < off) return;

    dim3 wg(WG);
    auto nb = [](long long total) { return dim3((unsigned)((total + WG - 1) / WG)); };
    dim3 nb8((unsigned)((N + 7) / 8));    // k_mm5_final: 8 nodes/block
    dim3 nb16((unsigned)((N + 15) / 16)); // hop kernels: 16 nodes/block

    // ---- graph/normalization setup ----
    k_zero2<<<nb(N), wg, 0, stream>>>(deg, fill, N);
    k_count<<<nb(E), wg, 0, stream>>>(dst, deg, E);
    k_dis<<<nb(N), wg, 0, stream>>>(deg, dis, N);
    k_scan_blk<<<dim3(nscan), dim3(1024), 0, stream>>>(deg, rowptr, bsum, N);
    k_scan_top<<<dim3(1), dim3(64), 0, stream>>>(bsum, rowptr + N, nscan);
    k_scan_add<<<nb(N), wg, 0, stream>>>(rowptr, bsum, N);
    k_scatter<<<nb(E), wg, 0, stream>>>(src, dst, rowptr, fill, dis, emeta, E);

    // ---- h0 = X^T -> [n][w][4b] ----
    k_xpose<<<nb((long long)N * 20), wg, 0, stream>>>(X, h20a, N);

    float* out_pred = (float*)d_out;
    float* out_h    = (float*)d_out + (size_t)4 * N;

    // ---- layer 0 (5 -> 32), f32 ----
    k_mm5<<<nb((long long)N * 128), wg, 0, stream>>>(h20a, W0, acc, N, 1);
    k_spmm20<<<nb((long long)N * 5), wg, 0, stream>>>(rowptr, emeta, h20a, h20b, N);
    k_mm5<<<nb((long long)N * 128), wg, 0, stream>>>(h20b, W0 + 160, acc, N, 0);
    k_spmm20<<<nb((long long)N * 5), wg, 0, stream>>>(rowptr, emeta, h20b, h20a, N);
    k_mm5<<<nb((long long)N * 128), wg, 0, stream>>>(h20a, W0 + 320, acc, N, 0);
    k_spmm20<<<nb((long long)N * 5), wg, 0, stream>>>(rowptr, emeta, h20a, h20b, N);
    k_mm5_final<<<nb8, wg, 0, stream>>>(h20b, W0 + 480, b0, acc, (uint2*)h16a, W1, acc, N);

    // ---- layer 1 (32 -> 32), fp16 node storage ----
    k_hop_fused<<<nb16, wg, 0, stream>>>(rowptr, emeta, (const uint4*)h16a, (uint4*)h16b,
                                         W1 + 1024, acc, N);
    k_hop_fused<<<nb16, wg, 0, stream>>>(rowptr, emeta, (const uint4*)h16b, (uint4*)h16a,
                                         W1 + 2048, acc, N);
    k_hop_last<1><<<nb16, wg, 0, stream>>>(rowptr, emeta, (const uint4*)h16a, W1 + 3072,
                                           acc, b1, (uint4*)h16b, W2, acc,
                                           nullptr, nullptr, nullptr, nullptr, N);

    // ---- layer 2 (32 -> 32) ----
    k_hop_fused<<<nb16, wg, 0, stream>>>(rowptr, emeta, (const uint4*)h16b, (uint4*)h16a,
                                         W2 + 1024, acc, N);
    k_hop_fused<<<nb16, wg, 0, stream>>>(rowptr, emeta, (const uint4*)h16a, (uint4*)h16b,
                                         W2 + 2048, acc, N);
    k_hop_last<2><<<nb16, wg, 0, stream>>>(rowptr, emeta, (const uint4*)h16b, W2 + 3072,
                                           acc, b2, nullptr, nullptr, nullptr,
                                           out_h, Wr, br, out_pred, N);
}

// Round 11
// 565.127 us; speedup vs baseline: 1.1722x; 1.1722x over previous
//
#include <hip/hip_runtime.h>
#include <hip/hip_fp16.h>

#define WG 256

// ---- fp16 helpers: 4 channels <-> uint2 ----
__device__ __forceinline__ float4 h4_to_f4(uint2 u) {
    union { unsigned int x; __half2 h; } a, b;
    a.x = u.x; b.x = u.y;
    float2 f0 = __half22float2(a.h);
    float2 f1 = __half22float2(b.h);
    return make_float4(f0.x, f0.y, f1.x, f1.y);
}
__device__ __forceinline__ uint2 f4_to_h4(float4 v) {
    union { unsigned int x; __half2 h; } a, b;
    a.h = __floats2half2_rn(v.x, v.y);
    b.h = __floats2half2_rn(v.z, v.w);
    return make_uint2(a.x, b.x);
}

// ---------------- setup kernels ----------------

__global__ void k_zero2(int* __restrict__ a, int* __restrict__ b, int n) {
    int i = blockIdx.x * blockDim.x + threadIdx.x;
    if (i < n) { a[i] = 0; b[i] = 0; }
}

__global__ void k_count(const int* __restrict__ dst, int* __restrict__ deg, int E) {
    int e = blockIdx.x * blockDim.x + threadIdx.x;
    if (e < E) atomicAdd(&deg[dst[e]], 1);
}

__global__ void k_dis(const int* __restrict__ deg, float* __restrict__ dis, int N) {
    int n = blockIdx.x * blockDim.x + threadIdx.x;
    if (n < N) {
        int d = deg[n];
        dis[n] = (d > 0) ? rsqrtf((float)d) : 0.0f;
    }
}

// ---- hierarchical scan ----
__global__ __launch_bounds__(1024) void k_scan_blk(const int* __restrict__ deg,
                                                   int* __restrict__ rowptr,
                                                   int* __restrict__ bsum, int N) {
    __shared__ int s[1024];
    int t = threadIdx.x;
    int gid = blockIdx.x * 1024 + t;
    int v = (gid < N) ? deg[gid] : 0;
    s[t] = v;
    __syncthreads();
    for (int off = 1; off < 1024; off <<= 1) {
        int u = (t >= off) ? s[t - off] : 0;
        __syncthreads();
        s[t] += u;
        __syncthreads();
    }
    if (gid < N) rowptr[gid] = s[t] - v;
    if (t == 1023) bsum[blockIdx.x] = s[1023];
}

__global__ void k_scan_top(int* __restrict__ bsum, int* __restrict__ rowptr_last, int nb) {
    if (threadIdx.x == 0 && blockIdx.x == 0) {
        int run = 0;
        for (int i = 0; i < nb; ++i) { int v = bsum[i]; bsum[i] = run; run += v; }
        *rowptr_last = run;
    }
}

__global__ void k_scan_add(int* __restrict__ rowptr, const int* __restrict__ bsum, int N) {
    int gid = blockIdx.x * blockDim.x + threadIdx.x;
    if (gid < N) rowptr[gid] += bsum[gid >> 10];
}

__global__ void k_scatter(const int* __restrict__ src, const int* __restrict__ dst,
                          const int* __restrict__ rowptr, int* __restrict__ fill,
                          const float* __restrict__ dis,
                          int2* __restrict__ emeta, int E) {
    int e = blockIdx.x * blockDim.x + threadIdx.x;
    if (e >= E) return;
    int d = dst[e], s = src[e];
    int slot = rowptr[d] + atomicAdd(&fill[d], 1);
    emeta[slot] = make_int2(s, __float_as_int(dis[s] * dis[d]));
}

// X (B,WIN,N) f32 -> h0 [n][w][b] f32
__global__ void k_xpose(const float* __restrict__ X, float* __restrict__ h0, int N) {
    long long tid = (long long)blockIdx.x * blockDim.x + threadIdx.x;
    if (tid >= (long long)N * 20) return;
    int n = (int)(tid / 20), r = (int)(tid % 20);
    int b = r & 3, w = r >> 2;
    h0[tid] = X[(size_t)(b * 5 + w) * N + n];
}

// ---------------- layer-0 propagation (f32, table L2-resident) ----------------
__global__ void k_spmm20(const int* __restrict__ rowptr, const int2* __restrict__ emeta,
                         const float* __restrict__ hin, float* __restrict__ hout, int N) {
    long long tid = (long long)blockIdx.x * blockDim.x + threadIdx.x;
    if (tid >= (long long)N * 5) return;
    int n = (int)(tid / 5), w = (int)(tid % 5);
    const float4* hin4 = (const float4*)hin;
    float ax = 0.f, ay = 0.f, az = 0.f, aw = 0.f;
    float bx = 0.f, by = 0.f, bz = 0.f, bw = 0.f;
    int j = rowptr[n], j1 = rowptr[n + 1];
    for (; j + 1 < j1; j += 2) {
        int2 m0 = emeta[j], m1 = emeta[j + 1];
        float4 g0 = hin4[(size_t)m0.x * 5 + w];
        float4 g1 = hin4[(size_t)m1.x * 5 + w];
        float w0 = __int_as_float(m0.y), w1 = __int_as_float(m1.y);
        ax += w0 * g0.x; ay += w0 * g0.y; az += w0 * g0.z; aw += w0 * g0.w;
        bx += w1 * g1.x; by += w1 * g1.y; bz += w1 * g1.z; bw += w1 * g1.w;
    }
    if (j < j1) {
        int2 m = emeta[j];
        float4 g = hin4[(size_t)m.x * 5 + w];
        float wt = __int_as_float(m.y);
        ax += wt * g.x; ay += wt * g.y; az += wt * g.z; aw += wt * g.w;
    }
    float4 o; o.x = ax + bx; o.y = ay + by; o.z = az + bz; o.w = aw + bw;
    ((float4*)hout)[(size_t)n * 5 + w] = o;
}

// acc[n][b][o] (+)= sum_w h[n][w][b] * W[w][o]
__global__ void k_mm5(const float* __restrict__ h, const float* __restrict__ W,
                      float* __restrict__ acc, int N, int first) {
    __shared__ float w[5 * 32];
    int t = threadIdx.x;
    if (t < 160) w[t] = W[t];
    __syncthreads();
    long long tid = (long long)blockIdx.x * WG + t;
    int node = (int)(tid >> 7);
    if (node >= N) return;
    int b = ((int)tid >> 5) & 3, o = (int)tid & 31;
    const float* hp = h + (size_t)node * 20 + b;
    float a = first ? 0.0f : acc[tid];
#pragma unroll
    for (int f = 0; f < 5; ++f) a += hp[f * 4] * w[f * 32 + o];
    acc[tid] = a;
}

// layer-0 tail: acc += h20*W0[3]; v=tanh(acc+b0); hout(fp16)=v; acc_out = v*Wnext[k=0]
__global__ __launch_bounds__(256) void k_mm5_final(const float* __restrict__ h20,
                                                   const float* __restrict__ W03,
                                                   const float* __restrict__ bias,
                                                   const float* __restrict__ acc_in,
                                                   uint2* __restrict__ hout,
                                                   const float* __restrict__ Wnext,
                                                   float* __restrict__ acc_out, int N) {
    __shared__ float4 wn4[256];
    __shared__ float4 w03[40];
    __shared__ float  hs[8 * 132];
    int t = threadIdx.x;
    wn4[t] = ((const float4*)Wnext)[t];
    if (t < 40) w03[t] = ((const float4*)W03)[t];
    __syncthreads();
    int nl = t >> 5, lane = t & 31, b = lane >> 3, q = lane & 7;
    int n = blockIdx.x * 8 + nl;
    bool valid = (n < N);
    float4 v4 = make_float4(0.f, 0.f, 0.f, 0.f);
    if (valid) {
        float4 a = ((const float4*)acc_in)[(size_t)n * 32 + lane];
#pragma unroll
        for (int w = 0; w < 5; ++w) {
            float hv = h20[(size_t)n * 20 + w * 4 + b];
            float4 wv = w03[w * 8 + q];
            a.x += hv * wv.x; a.y += hv * wv.y; a.z += hv * wv.z; a.w += hv * wv.w;
        }
        float4 b4 = ((const float4*)bias)[q];
        v4.x = tanhf(a.x + b4.x); v4.y = tanhf(a.y + b4.y);
        v4.z = tanhf(a.z + b4.z); v4.w = tanhf(a.w + b4.w);
        hout[(size_t)n * 32 + lane] = f4_to_h4(v4);
    }
    float* hrow = &hs[nl * 132 + b * 33 + q * 4];
    hrow[0] = v4.x; hrow[1] = v4.y; hrow[2] = v4.z; hrow[3] = v4.w;
    __syncthreads();
    float sx = 0.f, sy = 0.f, sz = 0.f, sw = 0.f;
    const float* hb = &hs[nl * 132 + b * 33];
#pragma unroll
    for (int f = 0; f < 32; ++f) {
        float hv = hb[f];
        float4 wv = wn4[f * 8 + q];
        sx += hv * wv.x; sy += hv * wv.y; sz += hv * wv.z; sw += hv * wv.w;
    }
    if (valid) {
        float4 o; o.x = sx; o.y = sy; o.z = sz; o.w = sw;
        ((float4*)acc_out)[(size_t)n * 32 + lane] = o;
    }
}

// ============== fused hops: 32 lanes/node, uint2 gathers (round-5 structure) ==============
// Template U = gather unroll depth (loads in flight per wave). Round 5 = U4 @ 88 VGPR.
// Within-probe A/B this round: layer 1 = U8, layer 2 = U4.

template <int U>
__device__ __forceinline__ float4 gather32(const int* __restrict__ rowptr,
                                           const int2* __restrict__ emeta,
                                           const uint2* __restrict__ hin,
                                           int n, int lane) {
    float a0 = 0.f, a1 = 0.f, a2 = 0.f, a3 = 0.f;
    float b0 = 0.f, b1 = 0.f, b2 = 0.f, b3 = 0.f;
    int j = rowptr[n], j1 = rowptr[n + 1];
    for (; j + U - 1 < j1; j += U) {
        int2  m[U];
        uint2 u[U];
#pragma unroll
        for (int k = 0; k < U; ++k) m[k] = emeta[j + k];
#pragma unroll
        for (int k = 0; k < U; ++k) u[k] = hin[(size_t)m[k].x * 32 + lane];
#pragma unroll
        for (int k = 0; k < U; ++k) {
            float w = __int_as_float(m[k].y);
            float4 g = h4_to_f4(u[k]);
            if (k & 1) { b0 += w * g.x; b1 += w * g.y; b2 += w * g.z; b3 += w * g.w; }
            else       { a0 += w * g.x; a1 += w * g.y; a2 += w * g.z; a3 += w * g.w; }
        }
    }
    for (; j < j1; ++j) {
        int2 m = emeta[j];
        float w = __int_as_float(m.y);
        float4 g = h4_to_f4(hin[(size_t)m.x * 32 + lane]);
        a0 += w * g.x; a1 += w * g.y; a2 += w * g.z; a3 += w * g.w;
    }
    return make_float4(a0 + b0, a1 + b1, a2 + b2, a3 + b3);
}

// mid hop: hnext = A*hin (fp16); acc += hnext * Wk
template <int U>
__global__ __launch_bounds__(256) void k_hop_fused(const int* __restrict__ rowptr,
                                                   const int2* __restrict__ emeta,
                                                   const uint2* __restrict__ hin,
                                                   uint2* __restrict__ hnext,
                                                   const float* __restrict__ Wk,
                                                   float* __restrict__ acc, int N) {
    __shared__ float4 ws4[256];
    __shared__ float  hs[8 * 132];

    int t = threadIdx.x;
    ws4[t] = ((const float4*)Wk)[t];

    int nl = t >> 5, lane = t & 31;
    int n = blockIdx.x * 8 + nl;
    bool valid = (n < N);

    float4 av = make_float4(0.f, 0.f, 0.f, 0.f);
    if (valid) {
        av = gather32<U>(rowptr, emeta, hin, n, lane);
        hnext[(size_t)n * 32 + lane] = f4_to_h4(av);
    }

    int b = lane >> 3, q = lane & 7;
    float* hrow = &hs[nl * 132 + b * 33 + q * 4];
    hrow[0] = av.x; hrow[1] = av.y; hrow[2] = av.z; hrow[3] = av.w;
    __syncthreads();
    if (!valid) return;

    float rx = 0.f, ry = 0.f, rz = 0.f, rw = 0.f;
    const float* hb = &hs[nl * 132 + b * 33];
#pragma unroll
    for (int f = 0; f < 32; ++f) {
        float hv = hb[f];
        float4 wv = ws4[f * 8 + q];
        rx += hv * wv.x; ry += hv * wv.y; rz += hv * wv.z; rw += hv * wv.w;
    }
    float4* accp = (float4*)acc + (size_t)n * 32 + lane;
    float4 cur = *accp;
    cur.x += rx; cur.y += ry; cur.z += rz; cur.w += rw;
    *accp = cur;
}

// last hop of a layer:
// MODE 1: v=tanh(acc+h'*Wk+b); hout(fp16)=v; acc_out = v*Wnext (next layer k=0)
// MODE 2: v=tanh(acc+h'*Wk+b); out_h(f32)=v; pred = v.Wr + br
template <int MODE, int U>
__global__ __launch_bounds__(256) void k_hop_last(const int* __restrict__ rowptr,
                                                  const int2* __restrict__ emeta,
                                                  const uint2* __restrict__ hin,
                                                  const float* __restrict__ Wk,
                                                  const float* __restrict__ acc_in,
                                                  const float* __restrict__ bias,
                                                  uint2* __restrict__ hout,
                                                  const float* __restrict__ Wnext,
                                                  float* __restrict__ acc_out,
                                                  float* __restrict__ out_h,
                                                  const float* __restrict__ Wr,
                                                  const float* __restrict__ br,
                                                  float* __restrict__ pred, int N) {
    __shared__ float4 ws4[256];
    __shared__ float4 wn4[MODE == 1 ? 256 : 1];
    __shared__ float  hs[8 * 132];

    int t = threadIdx.x;
    ws4[t] = ((const float4*)Wk)[t];
    if (MODE == 1) wn4[t] = ((const float4*)Wnext)[t];

    int nl = t >> 5, lane = t & 31;
    int n = blockIdx.x * 8 + nl;
    bool valid = (n < N);
    int b = lane >> 3, q = lane & 7;

    float4 av = make_float4(0.f, 0.f, 0.f, 0.f);
    if (valid) av = gather32<U>(rowptr, emeta, hin, n, lane);

    float* hrow = &hs[nl * 132 + b * 33 + q * 4];
    hrow[0] = av.x; hrow[1] = av.y; hrow[2] = av.z; hrow[3] = av.w;
    __syncthreads();

    float rx = 0.f, ry = 0.f, rz = 0.f, rw = 0.f;
    const float* hb = &hs[nl * 132 + b * 33];
#pragma unroll
    for (int f = 0; f < 32; ++f) {
        float hv = hb[f];
        float4 wv = ws4[f * 8 + q];
        rx += hv * wv.x; ry += hv * wv.y; rz += hv * wv.z; rw += hv * wv.w;
    }

    float4 v4 = make_float4(0.f, 0.f, 0.f, 0.f);
    if (valid) {
        float4 a = ((const float4*)acc_in)[(size_t)n * 32 + lane];
        float4 b4 = ((const float4*)bias)[q];
        v4.x = tanhf(a.x + rx + b4.x);
        v4.y = tanhf(a.y + ry + b4.y);
        v4.z = tanhf(a.z + rz + b4.z);
        v4.w = tanhf(a.w + rw + b4.w);
    }

    if (MODE == 1) {
        if (valid) hout[(size_t)n * 32 + lane] = f4_to_h4(v4);
        __syncthreads();            // all reads of hs (h') complete
        hrow[0] = v4.x; hrow[1] = v4.y; hrow[2] = v4.z; hrow[3] = v4.w;
        __syncthreads();
        float sx = 0.f, sy = 0.f, sz = 0.f, sw = 0.f;
#pragma unroll
        for (int f = 0; f < 32; ++f) {
            float hv = hb[f];
            float4 wv = wn4[f * 8 + q];
            sx += hv * wv.x; sy += hv * wv.y; sz += hv * wv.z; sw += hv * wv.w;
        }
        if (valid) {
            float4 o; o.x = sx; o.y = sy; o.z = sz; o.w = sw;
            ((float4*)acc_out)[(size_t)n * 32 + lane] = o;
        }
    } else {
        if (valid) {
            ((float4*)out_h)[((size_t)b * N + n) * 8 + q] = v4;
            float4 wr4 = ((const float4*)Wr)[q];
            float p = v4.x * wr4.x + v4.y * wr4.y + v4.z * wr4.z + v4.w * wr4.w;
            p += __shfl_xor(p, 1);
            p += __shfl_xor(p, 2);
            p += __shfl_xor(p, 4);
            if (q == 0) pred[(size_t)b * N + n] = p + br[0];
        }
    }
}

// ---------------- driver ----------------

extern "C" void kernel_launch(void* const* d_in, const int* in_sizes, int n_in,
                              void* d_out, int out_size, void* d_ws, size_t ws_size,
                              hipStream_t stream) {
    const float* X  = (const float*)d_in[0];
    const int*   ei = (const int*)d_in[1];
    const float* W0 = (const float*)d_in[2];
    const float* b0 = (const float*)d_in[3];
    const float* W1 = (const float*)d_in[4];
    const float* b1 = (const float*)d_in[5];
    const float* W2 = (const float*)d_in[6];
    const float* b2 = (const float*)d_in[7];
    const float* Wr = (const float*)d_in[8];
    const float* br = (const float*)d_in[9];

    const int N = in_sizes[0] / 20;
    const int E = in_sizes[1] / 2;
    const int* src = ei;
    const int* dst = ei + E;
    const int nscan = (N + 1023) / 1024;

    char* ws = (char*)d_ws;
    size_t off = 0;
    auto take = [&](size_t bytes) -> char* {
        char* p = ws + off;
        off = (off + bytes + 255) & ~(size_t)255;
        return p;
    };
    int*   deg    = (int*)  take((size_t)N * 4);
    int*   fill   = (int*)  take((size_t)N * 4);
    int*   rowptr = (int*)  take(((size_t)N + 1) * 4);
    float* dis    = (float*)take((size_t)N * 4);
    int*   bsum   = (int*)  take((size_t)(nscan + 1) * 4);
    int2*  emeta  = (int2*) take((size_t)E * 8);
    float* acc    = (float*)take((size_t)N * 128 * 4);
    uint2* h16a   = (uint2*)take((size_t)N * 128 * 2);   // fp16 node features
    uint2* h16b   = (uint2*)take((size_t)N * 128 * 2);
    float* h20a   = (float*)take((size_t)N * 20 * 4);    // layer-0 f32 ping-pong
    float* h20b   = (float*)take((size_t)N * 20 * 4);
    if (ws_size < off) return;

    dim3 wg(WG);
    auto nb = [](long long total) { return dim3((unsigned)((total + WG - 1) / WG)); };
    dim3 nb8((unsigned)((N + 7) / 8));    // hop kernels + mm5_final: 8 nodes/block

    // ---- graph/normalization setup ----
    k_zero2<<<nb(N), wg, 0, stream>>>(deg, fill, N);
    k_count<<<nb(E), wg, 0, stream>>>(dst, deg, E);
    k_dis<<<nb(N), wg, 0, stream>>>(deg, dis, N);
    k_scan_blk<<<dim3(nscan), dim3(1024), 0, stream>>>(deg, rowptr, bsum, N);
    k_scan_top<<<dim3(1), dim3(64), 0, stream>>>(bsum, rowptr + N, nscan);
    k_scan_add<<<nb(N), wg, 0, stream>>>(rowptr, bsum, N);
    k_scatter<<<nb(E), wg, 0, stream>>>(src, dst, rowptr, fill, dis, emeta, E);

    // ---- h0 = X^T -> [n][w][4b] ----
    k_xpose<<<nb((long long)N * 20), wg, 0, stream>>>(X, h20a, N);

    float* out_pred = (float*)d_out;
    float* out_h    = (float*)d_out + (size_t)4 * N;

    // ---- layer 0 (5 -> 32), f32 ----
    k_mm5<<<nb((long long)N * 128), wg, 0, stream>>>(h20a, W0, acc, N, 1);
    k_spmm20<<<nb((long long)N * 5), wg, 0, stream>>>(rowptr, emeta, h20a, h20b, N);
    k_mm5<<<nb((long long)N * 128), wg, 0, stream>>>(h20b, W0 + 160, acc, N, 0);
    k_spmm20<<<nb((long long)N * 5), wg, 0, stream>>>(rowptr, emeta, h20b, h20a, N);
    k_mm5<<<nb((long long)N * 128), wg, 0, stream>>>(h20a, W0 + 320, acc, N, 0);
    k_spmm20<<<nb((long long)N * 5), wg, 0, stream>>>(rowptr, emeta, h20a, h20b, N);
    k_mm5_final<<<nb8, wg, 0, stream>>>(h20b, W0 + 480, b0, acc, h16a, W1, acc, N);

    // ---- layer 1 (32 -> 32): UNROLL=8 arm of the A/B ----
    k_hop_fused<8><<<nb8, wg, 0, stream>>>(rowptr, emeta, h16a, h16b, W1 + 1024, acc, N);
    k_hop_fused<8><<<nb8, wg, 0, stream>>>(rowptr, emeta, h16b, h16a, W1 + 2048, acc, N);
    k_hop_last<1, 8><<<nb8, wg, 0, stream>>>(rowptr, emeta, h16a, W1 + 3072, acc, b1,
                                             h16b, W2, acc, nullptr, nullptr, nullptr,
                                             nullptr, N);

    // ---- layer 2 (32 -> 32): UNROLL=4 arm (round-5 baseline) ----
    k_hop_fused<4><<<nb8, wg, 0, stream>>>(rowptr, emeta, h16b, h16a, W2 + 1024, acc, N);
    k_hop_fused<4><<<nb8, wg, 0, stream>>>(rowptr, emeta, h16a, h16b, W2 + 2048, acc, N);
    k_hop_last<2, 4><<<nb8, wg, 0, stream>>>(rowptr, emeta, h16b, W2 + 3072, acc, b2,
                                             nullptr, nullptr, nullptr,
                                             out_h, Wr, br, out_pred, N);
}

// Round 12
// 470.158 us; speedup vs baseline: 1.4089x; 1.2020x over previous
//
#include <hip/hip_runtime.h>
#include <hip/hip_fp16.h>

#define WG 256

// ---- fp16 helpers: 4 channels <-> uint2 ----
__device__ __forceinline__ float4 h4_to_f4(uint2 u) {
    union { unsigned int x; __half2 h; } a, b;
    a.x = u.x; b.x = u.y;
    float2 f0 = __half22float2(a.h);
    float2 f1 = __half22float2(b.h);
    return make_float4(f0.x, f0.y, f1.x, f1.y);
}
__device__ __forceinline__ uint2 f4_to_h4(float4 v) {
    union { unsigned int x; __half2 h; } a, b;
    a.h = __floats2half2_rn(v.x, v.y);
    b.h = __floats2half2_rn(v.z, v.w);
    return make_uint2(a.x, b.x);
}

// ---------------- setup kernels ----------------

__global__ void k_zero2(int* __restrict__ a, int* __restrict__ b, int n) {
    int i = blockIdx.x * blockDim.x + threadIdx.x;
    if (i < n) { a[i] = 0; b[i] = 0; }
}

__global__ void k_count(const int* __restrict__ dst, int* __restrict__ deg, int E) {
    int e = blockIdx.x * blockDim.x + threadIdx.x;
    if (e < E) atomicAdd(&deg[dst[e]], 1);
}

__global__ void k_dis(const int* __restrict__ deg, float* __restrict__ dis, int N) {
    int n = blockIdx.x * blockDim.x + threadIdx.x;
    if (n < N) {
        int d = deg[n];
        dis[n] = (d > 0) ? rsqrtf((float)d) : 0.0f;
    }
}

// ---- hierarchical scan ----
__global__ __launch_bounds__(1024) void k_scan_blk(const int* __restrict__ deg,
                                                   int* __restrict__ rowptr,
                                                   int* __restrict__ bsum, int N) {
    __shared__ int s[1024];
    int t = threadIdx.x;
    int gid = blockIdx.x * 1024 + t;
    int v = (gid < N) ? deg[gid] : 0;
    s[t] = v;
    __syncthreads();
    for (int off = 1; off < 1024; off <<= 1) {
        int u = (t >= off) ? s[t - off] : 0;
        __syncthreads();
        s[t] += u;
        __syncthreads();
    }
    if (gid < N) rowptr[gid] = s[t] - v;
    if (t == 1023) bsum[blockIdx.x] = s[1023];
}

__global__ void k_scan_top(int* __restrict__ bsum, int* __restrict__ rowptr_last, int nb) {
    if (threadIdx.x == 0 && blockIdx.x == 0) {
        int run = 0;
        for (int i = 0; i < nb; ++i) { int v = bsum[i]; bsum[i] = run; run += v; }
        *rowptr_last = run;
    }
}

__global__ void k_scan_add(int* __restrict__ rowptr, const int* __restrict__ bsum, int N) {
    int gid = blockIdx.x * blockDim.x + threadIdx.x;
    if (gid < N) rowptr[gid] += bsum[gid >> 10];
}

__global__ void k_scatter(const int* __restrict__ src, const int* __restrict__ dst,
                          const int* __restrict__ rowptr, int* __restrict__ fill,
                          const float* __restrict__ dis,
                          int2* __restrict__ emeta, int E) {
    int e = blockIdx.x * blockDim.x + threadIdx.x;
    if (e >= E) return;
    int d = dst[e], s = src[e];
    int slot = rowptr[d] + atomicAdd(&fill[d], 1);
    emeta[slot] = make_int2(s, __float_as_int(dis[s] * dis[d]));
}

// X (B,WIN,N) f32 -> h0 [n][w][b] f32
__global__ void k_xpose(const float* __restrict__ X, float* __restrict__ h0, int N) {
    long long tid = (long long)blockIdx.x * blockDim.x + threadIdx.x;
    if (tid >= (long long)N * 20) return;
    int n = (int)(tid / 20), r = (int)(tid % 20);
    int b = r & 3, w = r >> 2;
    h0[tid] = X[(size_t)(b * 5 + w) * N + n];
}

// ---------------- layer-0 propagation (f32, 4 MB table: L2-resident) ----------------
__global__ void k_spmm20(const int* __restrict__ rowptr, const int2* __restrict__ emeta,
                         const float* __restrict__ hin, float* __restrict__ hout, int N) {
    long long tid = (long long)blockIdx.x * blockDim.x + threadIdx.x;
    if (tid >= (long long)N * 5) return;
    int n = (int)(tid / 5), w = (int)(tid % 5);
    const float4* hin4 = (const float4*)hin;
    float ax = 0.f, ay = 0.f, az = 0.f, aw = 0.f;
    float bx = 0.f, by = 0.f, bz = 0.f, bw = 0.f;
    int j = rowptr[n], j1 = rowptr[n + 1];
    for (; j + 1 < j1; j += 2) {
        int2 m0 = emeta[j], m1 = emeta[j + 1];
        float4 g0 = hin4[(size_t)m0.x * 5 + w];
        float4 g1 = hin4[(size_t)m1.x * 5 + w];
        float w0 = __int_as_float(m0.y), w1 = __int_as_float(m1.y);
        ax += w0 * g0.x; ay += w0 * g0.y; az += w0 * g0.z; aw += w0 * g0.w;
        bx += w1 * g1.x; by += w1 * g1.y; bz += w1 * g1.z; bw += w1 * g1.w;
    }
    if (j < j1) {
        int2 m = emeta[j];
        float4 g = hin4[(size_t)m.x * 5 + w];
        float wt = __int_as_float(m.y);
        ax += wt * g.x; ay += wt * g.y; az += wt * g.z; aw += wt * g.w;
    }
    float4 o; o.x = ax + bx; o.y = ay + by; o.z = az + bz; o.w = aw + bw;
    ((float4*)hout)[(size_t)n * 5 + w] = o;
}

// acc[n][b][o] (+)= sum_w h[n][w][b] * W[w][o]
__global__ void k_mm5(const float* __restrict__ h, const float* __restrict__ W,
                      float* __restrict__ acc, int N, int first) {
    __shared__ float w[5 * 32];
    int t = threadIdx.x;
    if (t < 160) w[t] = W[t];
    __syncthreads();
    long long tid = (long long)blockIdx.x * WG + t;
    int node = (int)(tid >> 7);
    if (node >= N) return;
    int b = ((int)tid >> 5) & 3, o = (int)tid & 31;
    const float* hp = h + (size_t)node * 20 + b;
    float a = first ? 0.0f : acc[tid];
#pragma unroll
    for (int f = 0; f < 5; ++f) a += hp[f * 4] * w[f * 32 + o];
    acc[tid] = a;
}

// layer-0 tail: v = tanh(acc + h20*W0[3] + b0); write h0 of layer 1 (fp16)
__global__ __launch_bounds__(256) void k_mm5_final(const float* __restrict__ h20,
                                                   const float* __restrict__ W03,
                                                   const float* __restrict__ bias,
                                                   const float* __restrict__ acc_in,
                                                   uint2* __restrict__ hout, int N) {
    __shared__ float4 w03[40];
    int t = threadIdx.x;
    if (t < 40) w03[t] = ((const float4*)W03)[t];
    __syncthreads();
    int nl = t >> 5, lane = t & 31, b = lane >> 3, q = lane & 7;
    int n = blockIdx.x * 8 + nl;
    if (n >= N) return;
    float4 a = ((const float4*)acc_in)[(size_t)n * 32 + lane];
#pragma unroll
    for (int w = 0; w < 5; ++w) {
        float hv = h20[(size_t)n * 20 + w * 4 + b];
        float4 wv = w03[w * 8 + q];
        a.x += hv * wv.x; a.y += hv * wv.y; a.z += hv * wv.z; a.w += hv * wv.w;
    }
    float4 b4 = ((const float4*)bias)[q];
    float4 v4;
    v4.x = tanhf(a.x + b4.x); v4.y = tanhf(a.y + b4.y);
    v4.z = tanhf(a.z + b4.z); v4.w = tanhf(a.w + b4.w);
    hout[(size_t)n * 32 + lane] = f4_to_h4(v4);
}

// ---------------- gather core: 32 lanes/node, uint2 (8 B) loads ----------------
template <int U>
__device__ __forceinline__ float4 gather32(const int* __restrict__ rowptr,
                                           const int2* __restrict__ emeta,
                                           const uint2* __restrict__ hin,
                                           int n, int lane) {
    float a0 = 0.f, a1 = 0.f, a2 = 0.f, a3 = 0.f;
    float b0 = 0.f, b1 = 0.f, b2 = 0.f, b3 = 0.f;
    int j = rowptr[n], j1 = rowptr[n + 1];
    for (; j + U - 1 < j1; j += U) {
        int2  m[U];
        uint2 u[U];
#pragma unroll
        for (int k = 0; k < U; ++k) m[k] = emeta[j + k];
#pragma unroll
        for (int k = 0; k < U; ++k) u[k] = hin[(size_t)m[k].x * 32 + lane];
#pragma unroll
        for (int k = 0; k < U; ++k) {
            float w = __int_as_float(m[k].y);
            float4 g = h4_to_f4(u[k]);
            if (k & 1) { b0 += w * g.x; b1 += w * g.y; b2 += w * g.z; b3 += w * g.w; }
            else       { a0 += w * g.x; a1 += w * g.y; a2 += w * g.z; a3 += w * g.w; }
        }
    }
    for (; j < j1; ++j) {
        int2 m = emeta[j];
        float w = __int_as_float(m.y);
        float4 g = h4_to_f4(hin[(size_t)m.x * 32 + lane]);
        a0 += w * g.x; a1 += w * g.y; a2 += w * g.z; a3 += w * g.w;
    }
    return make_float4(a0 + b0, a1 + b1, a2 + b2, a3 + b3);
}

// ---------------- LEAN hop: h_out = A * h_in (fp16), nothing else ----------------
// No LDS, no matmul, no acc: ~40-50 VGPR -> 8 waves/SIMD (occupancy experiment).
__global__ __launch_bounds__(256) void k_hop(const int* __restrict__ rowptr,
                                             const int2* __restrict__ emeta,
                                             const uint2* __restrict__ hin,
                                             uint2* __restrict__ hout, int N) {
    int t = threadIdx.x;
    int nl = t >> 5, lane = t & 31;
    int n = blockIdx.x * 8 + nl;
    if (n >= N) return;
    float4 av = gather32<4>(rowptr, emeta, hin, n, lane);
    hout[(size_t)n * 32 + lane] = f4_to_h4(av);
}

// ---------------- per-layer combine: v = tanh(sum_k h_k W_k + b) ----------------
// Full (4,32,32) W staged in LDS; its flat [k*32+f][o] layout IS the input tensor.
// MODE 1: write h' fp16 (in-place over h0 is safe: same thread reads & writes idx)
// MODE 2: write out_h f32 (b*N+n layout) + pred
template <int MODE>
__global__ __launch_bounds__(256) void k_combine(const uint2* __restrict__ h0,
                                                 const uint2* __restrict__ h1,
                                                 const uint2* __restrict__ h2,
                                                 const uint2* __restrict__ h3,
                                                 const float* __restrict__ W,
                                                 const float* __restrict__ bias,
                                                 uint2* __restrict__ hout,
                                                 float* __restrict__ out_h,
                                                 const float* __restrict__ Wr,
                                                 const float* __restrict__ br,
                                                 float* __restrict__ pred, int N) {
    __shared__ float4 ws4[1024];      // (4,32,32) weights, 16 KB
    __shared__ float  hs[32 * 132];   // 8 nodes x 4 b x (128 + 4 pad), 16.9 KB

    int t = threadIdx.x;
    const float4* W4 = (const float4*)W;
#pragma unroll
    for (int i = 0; i < 4; ++i) ws4[t + i * 256] = W4[t + i * 256];

    int nl = t >> 5, lane = t & 31, b = lane >> 3, q = lane & 7;
    int n = blockIdx.x * 8 + nl;
    bool valid = (n < N);
    int nb = nl * 4 + b;
    float* hrow = &hs[nb * 132 + q * 4];

    if (valid) {
        size_t idx = (size_t)n * 32 + lane;
        *(float4*)(hrow)      = h4_to_f4(h0[idx]);
        *(float4*)(hrow + 32) = h4_to_f4(h1[idx]);
        *(float4*)(hrow + 64) = h4_to_f4(h2[idx]);
        *(float4*)(hrow + 96) = h4_to_f4(h3[idx]);
    } else {
        float4 z = make_float4(0.f, 0.f, 0.f, 0.f);
        *(float4*)(hrow) = z; *(float4*)(hrow + 32) = z;
        *(float4*)(hrow + 64) = z; *(float4*)(hrow + 96) = z;
    }
    __syncthreads();

    float sx = 0.f, sy = 0.f, sz = 0.f, sw = 0.f;
    const float* hb = &hs[nb * 132];
#pragma unroll 16
    for (int kf = 0; kf < 128; ++kf) {
        float hv = hb[kf];
        float4 wv = ws4[kf * 8 + q];
        sx += hv * wv.x; sy += hv * wv.y; sz += hv * wv.z; sw += hv * wv.w;
    }

    if (!valid) return;
    float4 b4 = ((const float4*)bias)[q];
    float4 v4;
    v4.x = tanhf(sx + b4.x); v4.y = tanhf(sy + b4.y);
    v4.z = tanhf(sz + b4.z); v4.w = tanhf(sw + b4.w);

    if (MODE == 1) {
        hout[(size_t)n * 32 + lane] = f4_to_h4(v4);
    } else {
        ((float4*)out_h)[((size_t)b * N + n) * 8 + q] = v4;
        float4 wr4 = ((const float4*)Wr)[q];
        float p = v4.x * wr4.x + v4.y * wr4.y + v4.z * wr4.z + v4.w * wr4.w;
        p += __shfl_xor(p, 1);
        p += __shfl_xor(p, 2);
        p += __shfl_xor(p, 4);
        if (q == 0) pred[(size_t)b * N + n] = p + br[0];
    }
}

// ---------------- driver ----------------

extern "C" void kernel_launch(void* const* d_in, const int* in_sizes, int n_in,
                              void* d_out, int out_size, void* d_ws, size_t ws_size,
                              hipStream_t stream) {
    const float* X  = (const float*)d_in[0];
    const int*   ei = (const int*)d_in[1];
    const float* W0 = (const float*)d_in[2];
    const float* b0 = (const float*)d_in[3];
    const float* W1 = (const float*)d_in[4];
    const float* b1 = (const float*)d_in[5];
    const float* W2 = (const float*)d_in[6];
    const float* b2 = (const float*)d_in[7];
    const float* Wr = (const float*)d_in[8];
    const float* br = (const float*)d_in[9];

    const int N = in_sizes[0] / 20;
    const int E = in_sizes[1] / 2;
    const int* src = ei;
    const int* dst = ei + E;
    const int nscan = (N + 1023) / 1024;

    char* ws = (char*)d_ws;
    size_t off = 0;
    auto take = [&](size_t bytes) -> char* {
        char* p = ws + off;
        off = (off + bytes + 255) & ~(size_t)255;
        return p;
    };
    const size_t HBYTES = (size_t)N * 128 * 2;   // one fp16 node table (12.8 MB)
    int*   deg    = (int*)  take((size_t)N * 4);
    int*   fill   = (int*)  take((size_t)N * 4);
    int*   rowptr = (int*)  take(((size_t)N + 1) * 4);
    float* dis    = (float*)take((size_t)N * 4);
    int*   bsum   = (int*)  take((size_t)(nscan + 1) * 4);
    int2*  emeta  = (int2*) take((size_t)E * 8);
    char*  hAp    = take(HBYTES);
    char*  hBp    = take(HBYTES);
    char*  hCp    = take(HBYTES);
    char*  hDp    = take(HBYTES);   // hC,hD contiguous (HBYTES is 256-aligned)
    if (ws_size < off) return;

    uint2* hA = (uint2*)hAp;
    uint2* hB = (uint2*)hBp;
    uint2* hC = (uint2*)hCp;
    uint2* hD = (uint2*)hDp;
    // layer-0 aliases (dead before the aliased tables' first writes):
    float* acc  = (float*)hCp;                       // 25.6 MB over hC+hD
    float* h20a = (float*)hBp;                       // 4 MB
    float* h20b = (float*)(hBp + (size_t)N * 20 * 4);// 4 MB, inside hB

    dim3 wg(WG);
    auto nb = [](long long total) { return dim3((unsigned)((total + WG - 1) / WG)); };
    dim3 nb8((unsigned)((N + 7) / 8));   // hop/combine/mm5_final: 8 nodes per block

    // ---- graph/normalization setup ----
    k_zero2<<<nb(N), wg, 0, stream>>>(deg, fill, N);
    k_count<<<nb(E), wg, 0, stream>>>(dst, deg, E);
    k_dis<<<nb(N), wg, 0, stream>>>(deg, dis, N);
    k_scan_blk<<<dim3(nscan), dim3(1024), 0, stream>>>(deg, rowptr, bsum, N);
    k_scan_top<<<dim3(1), dim3(64), 0, stream>>>(bsum, rowptr + N, nscan);
    k_scan_add<<<nb(N), wg, 0, stream>>>(rowptr, bsum, N);
    k_scatter<<<nb(E), wg, 0, stream>>>(src, dst, rowptr, fill, dis, emeta, E);

    // ---- h0 = X^T -> [n][w][4b] ----
    k_xpose<<<nb((long long)N * 20), wg, 0, stream>>>(X, h20a, N);

    float* out_pred = (float*)d_out;
    float* out_h    = (float*)d_out + (size_t)4 * N;

    // ---- layer 0 (5 -> 32), f32 acc path ----
    k_mm5<<<nb((long long)N * 128), wg, 0, stream>>>(h20a, W0, acc, N, 1);
    k_spmm20<<<nb((long long)N * 5), wg, 0, stream>>>(rowptr, emeta, h20a, h20b, N);
    k_mm5<<<nb((long long)N * 128), wg, 0, stream>>>(h20b, W0 + 160, acc, N, 0);
    k_spmm20<<<nb((long long)N * 5), wg, 0, stream>>>(rowptr, emeta, h20b, h20a, N);
    k_mm5<<<nb((long long)N * 128), wg, 0, stream>>>(h20a, W0 + 320, acc, N, 0);
    k_spmm20<<<nb((long long)N * 5), wg, 0, stream>>>(rowptr, emeta, h20a, h20b, N);
    k_mm5_final<<<nb8, wg, 0, stream>>>(h20b, W0 + 480, b0, acc, hA, N);

    // ---- layer 1 (32 -> 32): 3 lean hops + combine ----
    k_hop<<<nb8, wg, 0, stream>>>(rowptr, emeta, hA, hB, N);
    k_hop<<<nb8, wg, 0, stream>>>(rowptr, emeta, hB, hC, N);
    k_hop<<<nb8, wg, 0, stream>>>(rowptr, emeta, hC, hD, N);
    k_combine<1><<<nb8, wg, 0, stream>>>(hA, hB, hC, hD, W1, b1, hA,
                                         nullptr, nullptr, nullptr, nullptr, N);

    // ---- layer 2 (32 -> 32): 3 lean hops + combine(out) ----
    k_hop<<<nb8, wg, 0, stream>>>(rowptr, emeta, hA, hB, N);
    k_hop<<<nb8, wg, 0, stream>>>(rowptr, emeta, hB, hC, N);
    k_hop<<<nb8, wg, 0, stream>>>(rowptr, emeta, hC, hD, N);
    k_combine<2><<<nb8, wg, 0, stream>>>(hA, hB, hC, hD, W2, b2, nullptr,
                                         out_h, Wr, br, out_pred, N);
}

// Round 13
// 416.296 us; speedup vs baseline: 1.5912x; 1.1294x over previous
//
#include <hip/hip_runtime.h>
#include <hip/hip_fp16.h>

#define WG 256

// ---- fp16 helpers: 4 channels <-> uint2 ----
__device__ __forceinline__ float4 h4_to_f4(uint2 u) {
    union { unsigned int x; __half2 h; } a, b;
    a.x = u.x; b.x = u.y;
    float2 f0 = __half22float2(a.h);
    float2 f1 = __half22float2(b.h);
    return make_float4(f0.x, f0.y, f1.x, f1.y);
}
__device__ __forceinline__ uint2 f4_to_h4(float4 v) {
    union { unsigned int x; __half2 h; } a, b;
    a.h = __floats2half2_rn(v.x, v.y);
    b.h = __floats2half2_rn(v.z, v.w);
    return make_uint2(a.x, b.x);
}

// ---------------- setup kernels ----------------

__global__ void k_zero2(int* __restrict__ a, int* __restrict__ b, int n) {
    int i = blockIdx.x * blockDim.x + threadIdx.x;
    if (i < n) { a[i] = 0; b[i] = 0; }
}

__global__ void k_count(const int* __restrict__ dst, int* __restrict__ deg, int E) {
    int e = blockIdx.x * blockDim.x + threadIdx.x;
    if (e < E) atomicAdd(&deg[dst[e]], 1);
}

__global__ void k_dis(const int* __restrict__ deg, float* __restrict__ dis, int N) {
    int n = blockIdx.x * blockDim.x + threadIdx.x;
    if (n < N) {
        int d = deg[n];
        dis[n] = (d > 0) ? rsqrtf((float)d) : 0.0f;
    }
}

// ---- hierarchical scan ----
__global__ __launch_bounds__(1024) void k_scan_blk(const int* __restrict__ deg,
                                                   int* __restrict__ rowptr,
                                                   int* __restrict__ bsum, int N) {
    __shared__ int s[1024];
    int t = threadIdx.x;
    int gid = blockIdx.x * 1024 + t;
    int v = (gid < N) ? deg[gid] : 0;
    s[t] = v;
    __syncthreads();
    for (int off = 1; off < 1024; off <<= 1) {
        int u = (t >= off) ? s[t - off] : 0;
        __syncthreads();
        s[t] += u;
        __syncthreads();
    }
    if (gid < N) rowptr[gid] = s[t] - v;
    if (t == 1023) bsum[blockIdx.x] = s[1023];
}

__global__ void k_scan_top(int* __restrict__ bsum, int* __restrict__ rowptr_last, int nb) {
    if (threadIdx.x == 0 && blockIdx.x == 0) {
        int run = 0;
        for (int i = 0; i < nb; ++i) { int v = bsum[i]; bsum[i] = run; run += v; }
        *rowptr_last = run;
    }
}

__global__ void k_scan_add(int* __restrict__ rowptr, const int* __restrict__ bsum, int N) {
    int gid = blockIdx.x * blockDim.x + threadIdx.x;
    if (gid < N) rowptr[gid] += bsum[gid >> 10];
}

__global__ void k_scatter(const int* __restrict__ src, const int* __restrict__ dst,
                          const int* __restrict__ rowptr, int* __restrict__ fill,
                          const float* __restrict__ dis,
                          int2* __restrict__ emeta, int E) {
    int e = blockIdx.x * blockDim.x + threadIdx.x;
    if (e >= E) return;
    int d = dst[e], s = src[e];
    int slot = rowptr[d] + atomicAdd(&fill[d], 1);
    emeta[slot] = make_int2(s, __float_as_int(dis[s] * dis[d]));
}

// X (B,WIN,N) f32 -> g0 [n][w][b] f32
__global__ void k_xpose(const float* __restrict__ X, float* __restrict__ h0, int N) {
    long long tid = (long long)blockIdx.x * blockDim.x + threadIdx.x;
    if (tid >= (long long)N * 20) return;
    int n = (int)(tid / 20), r = (int)(tid % 20);
    int b = r & 3, w = r >> 2;
    h0[tid] = X[(size_t)(b * 5 + w) * N + n];
}

// ---------------- layer-0 propagation (f32, 4 MB table: L2-resident) ----------------
__global__ void k_spmm20(const int* __restrict__ rowptr, const int2* __restrict__ emeta,
                         const float* __restrict__ hin, float* __restrict__ hout, int N) {
    long long tid = (long long)blockIdx.x * blockDim.x + threadIdx.x;
    if (tid >= (long long)N * 5) return;
    int n = (int)(tid / 5), w = (int)(tid % 5);
    const float4* hin4 = (const float4*)hin;
    float ax = 0.f, ay = 0.f, az = 0.f, aw = 0.f;
    float bx = 0.f, by = 0.f, bz = 0.f, bw = 0.f;
    int j = rowptr[n], j1 = rowptr[n + 1];
    for (; j + 1 < j1; j += 2) {
        int2 m0 = emeta[j], m1 = emeta[j + 1];
        float4 g0 = hin4[(size_t)m0.x * 5 + w];
        float4 g1 = hin4[(size_t)m1.x * 5 + w];
        float w0 = __int_as_float(m0.y), w1 = __int_as_float(m1.y);
        ax += w0 * g0.x; ay += w0 * g0.y; az += w0 * g0.z; aw += w0 * g0.w;
        bx += w1 * g1.x; by += w1 * g1.y; bz += w1 * g1.z; bw += w1 * g1.w;
    }
    if (j < j1) {
        int2 m = emeta[j];
        float4 g = hin4[(size_t)m.x * 5 + w];
        float wt = __int_as_float(m.y);
        ax += wt * g.x; ay += wt * g.y; az += wt * g.z; aw += wt * g.w;
    }
    float4 o; o.x = ax + bx; o.y = ay + by; o.z = az + bz; o.w = aw + bw;
    ((float4*)hout)[(size_t)n * 5 + w] = o;
}

// ---------------- layer-0 combine: v = tanh(sum_{k,w} g_k[n][w][b] * W0[k][w][o] + b0) ----------------
__global__ __launch_bounds__(256) void k_comb20(const float* __restrict__ g0,
                                                const float* __restrict__ g1,
                                                const float* __restrict__ g2,
                                                const float* __restrict__ g3,
                                                const float* __restrict__ W0,
                                                const float* __restrict__ bias,
                                                uint2* __restrict__ hout, int N) {
    __shared__ float4 ws[160];   // (4,5,32) = 640 floats
    int t = threadIdx.x;
    if (t < 160) ws[t] = ((const float4*)W0)[t];
    __syncthreads();
    long long tid = (long long)blockIdx.x * 256 + t;
    int n = (int)(tid >> 5);
    if (n >= N) return;
    int lane = (int)tid & 31, b = lane >> 3, q = lane & 7;
    float a0 = 0.f, a1 = 0.f, a2 = 0.f, a3 = 0.f;
    const float* gs[4] = {g0, g1, g2, g3};
#pragma unroll
    for (int k = 0; k < 4; ++k) {
        const float* g = gs[k];
#pragma unroll
        for (int w = 0; w < 5; ++w) {
            float hv = g[(size_t)n * 20 + w * 4 + b];
            float4 wv = ws[k * 40 + w * 8 + q];
            a0 += hv * wv.x; a1 += hv * wv.y; a2 += hv * wv.z; a3 += hv * wv.w;
        }
    }
    float4 b4 = ((const float4*)bias)[q];
    float4 v4;
    v4.x = tanhf(a0 + b4.x); v4.y = tanhf(a1 + b4.y);
    v4.z = tanhf(a2 + b4.z); v4.w = tanhf(a3 + b4.w);
    hout[(size_t)n * 32 + lane] = f4_to_h4(v4);
}

// ---------------- gather core: 32 lanes/node, uint2 (8 B) loads ----------------
template <int U>
__device__ __forceinline__ float4 gather32(const int* __restrict__ rowptr,
                                           const int2* __restrict__ emeta,
                                           const uint2* __restrict__ hin,
                                           int n, int lane) {
    float a0 = 0.f, a1 = 0.f, a2 = 0.f, a3 = 0.f;
    float b0 = 0.f, b1 = 0.f, b2 = 0.f, b3 = 0.f;
    int j = rowptr[n], j1 = rowptr[n + 1];
    for (; j + U - 1 < j1; j += U) {
        int2  m[U];
        uint2 u[U];
#pragma unroll
        for (int k = 0; k < U; ++k) m[k] = emeta[j + k];
#pragma unroll
        for (int k = 0; k < U; ++k) u[k] = hin[(size_t)m[k].x * 32 + lane];
#pragma unroll
        for (int k = 0; k < U; ++k) {
            float w = __int_as_float(m[k].y);
            float4 g = h4_to_f4(u[k]);
            if (k & 1) { b0 += w * g.x; b1 += w * g.y; b2 += w * g.z; b3 += w * g.w; }
            else       { a0 += w * g.x; a1 += w * g.y; a2 += w * g.z; a3 += w * g.w; }
        }
    }
    for (; j < j1; ++j) {
        int2 m = emeta[j];
        float w = __int_as_float(m.y);
        float4 g = h4_to_f4(hin[(size_t)m.x * 32 + lane]);
        a0 += w * g.x; a1 += w * g.y; a2 += w * g.z; a3 += w * g.w;
    }
    return make_float4(a0 + b0, a1 + b1, a2 + b2, a3 + b3);
}

// ---------------- LEAN hop: h_out = A * h_in (fp16) ----------------
__global__ __launch_bounds__(256) void k_hop(const int* __restrict__ rowptr,
                                             const int2* __restrict__ emeta,
                                             const uint2* __restrict__ hin,
                                             uint2* __restrict__ hout, int N) {
    int t = threadIdx.x;
    int nl = t >> 5, lane = t & 31;
    int n = blockIdx.x * 8 + nl;
    if (n >= N) return;
    float4 av = gather32<4>(rowptr, emeta, hin, n, lane);
    hout[(size_t)n * 32 + lane] = f4_to_h4(av);
}

// ---------------- 32-wide combine, R=2 rows/thread (W LDS-read amortized 2x) ------------
// Block: 256 threads = 16 nodes x 4 b x 8 q, each thread handles rows rr and rr+32.
// MODE 1: write h' fp16 (in-place over h0 safe: block-private indices, read pre-barrier)
// MODE 2: write out_h f32 (b*N+n layout) + pred
template <int MODE>
__global__ __launch_bounds__(256) void k_comb32(const uint2* __restrict__ h0,
                                                const uint2* __restrict__ h1,
                                                const uint2* __restrict__ h2,
                                                const uint2* __restrict__ h3,
                                                const float* __restrict__ W,
                                                const float* __restrict__ bias,
                                                uint2* __restrict__ hout,
                                                float* __restrict__ out_h,
                                                const float* __restrict__ Wr,
                                                const float* __restrict__ br,
                                                float* __restrict__ pred, int N) {
    __shared__ float4 ws4[1024];      // (4,32,32) weights, 16 KB
    __shared__ float  hs[64 * 132];   // 64 rows x (128 + 4 pad), 33.8 KB

    int t = threadIdx.x;
    const float4* W4 = (const float4*)W;
#pragma unroll
    for (int i = 0; i < 4; ++i) ws4[t + i * 256] = W4[t + i * 256];

    int q = t & 7, rr = t >> 3;       // rr in 0..31; rows rr and rr+32
    int n0 = blockIdx.x * 16;

#pragma unroll
    for (int rh = 0; rh < 2; ++rh) {
        int r = rr + rh * 32;
        int node = n0 + (r >> 2), b = r & 3;
        float* hrow = &hs[r * 132 + q * 4];
        if (node < N) {
            size_t idx = (size_t)node * 32 + b * 8 + q;
            *(float4*)(hrow)      = h4_to_f4(h0[idx]);
            *(float4*)(hrow + 32) = h4_to_f4(h1[idx]);
            *(float4*)(hrow + 64) = h4_to_f4(h2[idx]);
            *(float4*)(hrow + 96) = h4_to_f4(h3[idx]);
        } else {
            float4 z = make_float4(0.f, 0.f, 0.f, 0.f);
            *(float4*)(hrow) = z; *(float4*)(hrow + 32) = z;
            *(float4*)(hrow + 64) = z; *(float4*)(hrow + 96) = z;
        }
    }
    __syncthreads();

    float aA0 = 0.f, aA1 = 0.f, aA2 = 0.f, aA3 = 0.f;
    float aB0 = 0.f, aB1 = 0.f, aB2 = 0.f, aB3 = 0.f;
    const float* hbA = &hs[rr * 132];
    const float* hbB = &hs[(rr + 32) * 132];
#pragma unroll 16
    for (int kf = 0; kf < 128; ++kf) {
        float4 wv = ws4[kf * 8 + q];
        float hA = hbA[kf], hB = hbB[kf];
        aA0 += hA * wv.x; aA1 += hA * wv.y; aA2 += hA * wv.z; aA3 += hA * wv.w;
        aB0 += hB * wv.x; aB1 += hB * wv.y; aB2 += hB * wv.z; aB3 += hB * wv.w;
    }

    float4 b4 = ((const float4*)bias)[q];
    int bcol = rr & 3;
    int nA = n0 + (rr >> 2);
    int nB = nA + 8;
    float4 vA, vB;
    vA.x = tanhf(aA0 + b4.x); vA.y = tanhf(aA1 + b4.y);
    vA.z = tanhf(aA2 + b4.z); vA.w = tanhf(aA3 + b4.w);
    vB.x = tanhf(aB0 + b4.x); vB.y = tanhf(aB1 + b4.y);
    vB.z = tanhf(aB2 + b4.z); vB.w = tanhf(aB3 + b4.w);

    if (MODE == 1) {
        if (nA < N) hout[(size_t)nA * 32 + bcol * 8 + q] = f4_to_h4(vA);
        if (nB < N) hout[(size_t)nB * 32 + bcol * 8 + q] = f4_to_h4(vB);
    } else {
        float4 wr4 = ((const float4*)Wr)[q];
        float pA = vA.x * wr4.x + vA.y * wr4.y + vA.z * wr4.z + vA.w * wr4.w;
        float pB = vB.x * wr4.x + vB.y * wr4.y + vB.z * wr4.z + vB.w * wr4.w;
        pA += __shfl_xor(pA, 1); pA += __shfl_xor(pA, 2); pA += __shfl_xor(pA, 4);
        pB += __shfl_xor(pB, 1); pB += __shfl_xor(pB, 2); pB += __shfl_xor(pB, 4);
        if (nA < N) {
            ((float4*)out_h)[((size_t)bcol * N + nA) * 8 + q] = vA;
            if (q == 0) pred[(size_t)bcol * N + nA] = pA + br[0];
        }
        if (nB < N) {
            ((float4*)out_h)[((size_t)bcol * N + nB) * 8 + q] = vB;
            if (q == 0) pred[(size_t)bcol * N + nB] = pB + br[0];
        }
    }
}

// ---------------- driver ----------------

extern "C" void kernel_launch(void* const* d_in, const int* in_sizes, int n_in,
                              void* d_out, int out_size, void* d_ws, size_t ws_size,
                              hipStream_t stream) {
    const float* X  = (const float*)d_in[0];
    const int*   ei = (const int*)d_in[1];
    const float* W0 = (const float*)d_in[2];
    const float* b0 = (const float*)d_in[3];
    const float* W1 = (const float*)d_in[4];
    const float* b1 = (const float*)d_in[5];
    const float* W2 = (const float*)d_in[6];
    const float* b2 = (const float*)d_in[7];
    const float* Wr = (const float*)d_in[8];
    const float* br = (const float*)d_in[9];

    const int N = in_sizes[0] / 20;
    const int E = in_sizes[1] / 2;
    const int* src = ei;
    const int* dst = ei + E;
    const int nscan = (N + 1023) / 1024;

    char* ws = (char*)d_ws;
    size_t off = 0;
    auto take = [&](size_t bytes) -> char* {
        char* p = ws + off;
        off = (off + bytes + 255) & ~(size_t)255;
        return p;
    };
    const size_t HBYTES = (size_t)N * 128 * 2;   // fp16 node table (12.8 MB)
    const size_t GBYTES = (size_t)N * 20 * 4;    // layer-0 f32 table (4 MB)
    int*   deg    = (int*)  take((size_t)N * 4);
    int*   fill   = (int*)  take((size_t)N * 4);
    int*   rowptr = (int*)  take(((size_t)N + 1) * 4);
    float* dis    = (float*)take((size_t)N * 4);
    int*   bsum   = (int*)  take((size_t)(nscan + 1) * 4);
    int2*  emeta  = (int2*) take((size_t)E * 8);
    uint2* hA     = (uint2*)take(HBYTES);
    uint2* hB     = (uint2*)take(HBYTES);
    uint2* hC     = (uint2*)take(HBYTES);
    uint2* hD     = (uint2*)take(HBYTES);
    float* g0     = (float*)take(GBYTES);
    float* g1     = (float*)take(GBYTES);
    float* g2     = (float*)take(GBYTES);
    float* g3     = (float*)take(GBYTES);
    if (ws_size < off) return;

    dim3 wg(WG);
    auto nb = [](long long total) { return dim3((unsigned)((total + WG - 1) / WG)); };
    dim3 nb8((unsigned)((N + 7) / 8));     // hop: 8 nodes/block
    dim3 nb16((unsigned)((N + 15) / 16));  // comb32: 16 nodes/block

    // ---- graph/normalization setup ----
    k_zero2<<<nb(N), wg, 0, stream>>>(deg, fill, N);
    k_count<<<nb(E), wg, 0, stream>>>(dst, deg, E);
    k_dis<<<nb(N), wg, 0, stream>>>(deg, dis, N);
    k_scan_blk<<<dim3(nscan), dim3(1024), 0, stream>>>(deg, rowptr, bsum, N);
    k_scan_top<<<dim3(1), dim3(64), 0, stream>>>(bsum, rowptr + N, nscan);
    k_scan_add<<<nb(N), wg, 0, stream>>>(rowptr, bsum, N);
    k_scatter<<<nb(E), wg, 0, stream>>>(src, dst, rowptr, fill, dis, emeta, E);

    // ---- h0 = X^T -> [n][w][4b] ----
    k_xpose<<<nb((long long)N * 20), wg, 0, stream>>>(X, g0, N);

    float* out_pred = (float*)d_out;
    float* out_h    = (float*)d_out + (size_t)4 * N;

    // ---- layer 0 (5 -> 32): 3 lean f32 hops + combine ----
    k_spmm20<<<nb((long long)N * 5), wg, 0, stream>>>(rowptr, emeta, g0, g1, N);
    k_spmm20<<<nb((long long)N * 5), wg, 0, stream>>>(rowptr, emeta, g1, g2, N);
    k_spmm20<<<nb((long long)N * 5), wg, 0, stream>>>(rowptr, emeta, g2, g3, N);
    k_comb20<<<nb((long long)N * 32), wg, 0, stream>>>(g0, g1, g2, g3, W0, b0, hA, N);

    // ---- layer 1 (32 -> 32): 3 lean hops + combine ----
    k_hop<<<nb8, wg, 0, stream>>>(rowptr, emeta, hA, hB, N);
    k_hop<<<nb8, wg, 0, stream>>>(rowptr, emeta, hB, hC, N);
    k_hop<<<nb8, wg, 0, stream>>>(rowptr, emeta, hC, hD, N);
    k_comb32<1><<<nb16, wg, 0, stream>>>(hA, hB, hC, hD, W1, b1, hA,
                                         nullptr, nullptr, nullptr, nullptr, N);

    // ---- layer 2 (32 -> 32): 3 lean hops + combine(out) ----
    k_hop<<<nb8, wg, 0, stream>>>(rowptr, emeta, hA, hB, N);
    k_hop<<<nb8, wg, 0, stream>>>(rowptr, emeta, hB, hC, N);
    k_hop<<<nb8, wg, 0, stream>>>(rowptr, emeta, hC, hD, N);
    k_comb32<2><<<nb16, wg, 0, stream>>>(hA, hB, hC, hD, W2, b2, nullptr,
                                         out_h, Wr, br, out_pred, N);
}

// Round 14
// 376.435 us; speedup vs baseline: 1.7597x; 1.1059x over previous
//
#include <hip/hip_runtime.h>
#include <hip/hip_fp16.h>

#define WG 256

typedef _Float16 f16;
typedef f16 f16x8 __attribute__((ext_vector_type(8)));
typedef float f32x4 __attribute__((ext_vector_type(4)));

// ---- fp16 helpers: 4 channels <-> uint2 ----
__device__ __forceinline__ float4 h4_to_f4(uint2 u) {
    union { unsigned int x; __half2 h; } a, b;
    a.x = u.x; b.x = u.y;
    float2 f0 = __half22float2(a.h);
    float2 f1 = __half22float2(b.h);
    return make_float4(f0.x, f0.y, f1.x, f1.y);
}
__device__ __forceinline__ uint2 f4_to_h4(float4 v) {
    union { unsigned int x; __half2 h; } a, b;
    a.h = __floats2half2_rn(v.x, v.y);
    b.h = __floats2half2_rn(v.z, v.w);
    return make_uint2(a.x, b.x);
}

// ---------------- setup kernels ----------------

__global__ void k_zero2(int* __restrict__ a, int* __restrict__ b, int n) {
    int i = blockIdx.x * blockDim.x + threadIdx.x;
    if (i < n) { a[i] = 0; b[i] = 0; }
}

__global__ void k_count(const int* __restrict__ dst, int* __restrict__ deg, int E) {
    int e = blockIdx.x * blockDim.x + threadIdx.x;
    if (e < E) atomicAdd(&deg[dst[e]], 1);
}

__global__ void k_dis(const int* __restrict__ deg, float* __restrict__ dis, int N) {
    int n = blockIdx.x * blockDim.x + threadIdx.x;
    if (n < N) {
        int d = deg[n];
        dis[n] = (d > 0) ? rsqrtf((float)d) : 0.0f;
    }
}

// ---- hierarchical scan ----
__global__ __launch_bounds__(1024) void k_scan_blk(const int* __restrict__ deg,
                                                   int* __restrict__ rowptr,
                                                   int* __restrict__ bsum, int N) {
    __shared__ int s[1024];
    int t = threadIdx.x;
    int gid = blockIdx.x * 1024 + t;
    int v = (gid < N) ? deg[gid] : 0;
    s[t] = v;
    __syncthreads();
    for (int off = 1; off < 1024; off <<= 1) {
        int u = (t >= off) ? s[t - off] : 0;
        __syncthreads();
        s[t] += u;
        __syncthreads();
    }
    if (gid < N) rowptr[gid] = s[t] - v;
    if (t == 1023) bsum[blockIdx.x] = s[1023];
}

__global__ void k_scan_top(int* __restrict__ bsum, int* __restrict__ rowptr_last, int nb) {
    if (threadIdx.x == 0 && blockIdx.x == 0) {
        int run = 0;
        for (int i = 0; i < nb; ++i) { int v = bsum[i]; bsum[i] = run; run += v; }
        *rowptr_last = run;
    }
}

__global__ void k_scan_add(int* __restrict__ rowptr, const int* __restrict__ bsum, int N) {
    int gid = blockIdx.x * blockDim.x + threadIdx.x;
    if (gid < N) rowptr[gid] += bsum[gid >> 10];
}

__global__ void k_scatter(const int* __restrict__ src, const int* __restrict__ dst,
                          const int* __restrict__ rowptr, int* __restrict__ fill,
                          const float* __restrict__ dis,
                          int2* __restrict__ emeta, int E) {
    int e = blockIdx.x * blockDim.x + threadIdx.x;
    if (e >= E) return;
    int d = dst[e], s = src[e];
    int slot = rowptr[d] + atomicAdd(&fill[d], 1);
    emeta[slot] = make_int2(s, __float_as_int(dis[s] * dis[d]));
}

// X (B,WIN,N) f32 -> g0 [n][w][b] f32
__global__ void k_xpose(const float* __restrict__ X, float* __restrict__ h0, int N) {
    long long tid = (long long)blockIdx.x * blockDim.x + threadIdx.x;
    if (tid >= (long long)N * 20) return;
    int n = (int)(tid / 20), r = (int)(tid % 20);
    int b = r & 3, w = r >> 2;
    h0[tid] = X[(size_t)(b * 5 + w) * N + n];
}

// ---------------- layer-0 propagation (f32, 4 MB table: L2-resident) ----------------
__global__ void k_spmm20(const int* __restrict__ rowptr, const int2* __restrict__ emeta,
                         const float* __restrict__ hin, float* __restrict__ hout, int N) {
    long long tid = (long long)blockIdx.x * blockDim.x + threadIdx.x;
    if (tid >= (long long)N * 5) return;
    int n = (int)(tid / 5), w = (int)(tid % 5);
    const float4* hin4 = (const float4*)hin;
    float ax = 0.f, ay = 0.f, az = 0.f, aw = 0.f;
    float bx = 0.f, by = 0.f, bz = 0.f, bw = 0.f;
    int j = rowptr[n], j1 = rowptr[n + 1];
    for (; j + 1 < j1; j += 2) {
        int2 m0 = emeta[j], m1 = emeta[j + 1];
        float4 g0 = hin4[(size_t)m0.x * 5 + w];
        float4 g1 = hin4[(size_t)m1.x * 5 + w];
        float w0 = __int_as_float(m0.y), w1 = __int_as_float(m1.y);
        ax += w0 * g0.x; ay += w0 * g0.y; az += w0 * g0.z; aw += w0 * g0.w;
        bx += w1 * g1.x; by += w1 * g1.y; bz += w1 * g1.z; bw += w1 * g1.w;
    }
    if (j < j1) {
        int2 m = emeta[j];
        float4 g = hin4[(size_t)m.x * 5 + w];
        float wt = __int_as_float(m.y);
        ax += wt * g.x; ay += wt * g.y; az += wt * g.z; aw += wt * g.w;
    }
    float4 o; o.x = ax + bx; o.y = ay + by; o.z = az + bz; o.w = aw + bw;
    ((float4*)hout)[(size_t)n * 5 + w] = o;
}

// ---------------- layer-0 combine: v = tanh(sum_{k,w} g_k[n][w][b] * W0[k][w][o] + b0) ----------------
__global__ __launch_bounds__(256) void k_comb20(const float* __restrict__ g0,
                                                const float* __restrict__ g1,
                                                const float* __restrict__ g2,
                                                const float* __restrict__ g3,
                                                const float* __restrict__ W0,
                                                const float* __restrict__ bias,
                                                uint2* __restrict__ hout, int N) {
    __shared__ float4 ws[160];   // (4,5,32) = 640 floats
    int t = threadIdx.x;
    if (t < 160) ws[t] = ((const float4*)W0)[t];
    __syncthreads();
    long long tid = (long long)blockIdx.x * 256 + t;
    int n = (int)(tid >> 5);
    if (n >= N) return;
    int lane = (int)tid & 31, b = lane >> 3, q = lane & 7;
    float a0 = 0.f, a1 = 0.f, a2 = 0.f, a3 = 0.f;
    const float* gs[4] = {g0, g1, g2, g3};
#pragma unroll
    for (int k = 0; k < 4; ++k) {
        const float* g = gs[k];
#pragma unroll
        for (int w = 0; w < 5; ++w) {
            float hv = g[(size_t)n * 20 + w * 4 + b];
            float4 wv = ws[k * 40 + w * 8 + q];
            a0 += hv * wv.x; a1 += hv * wv.y; a2 += hv * wv.z; a3 += hv * wv.w;
        }
    }
    float4 b4 = ((const float4*)bias)[q];
    float4 v4;
    v4.x = tanhf(a0 + b4.x); v4.y = tanhf(a1 + b4.y);
    v4.z = tanhf(a2 + b4.z); v4.w = tanhf(a3 + b4.w);
    hout[(size_t)n * 32 + lane] = f4_to_h4(v4);
}

// ---------------- gather core: 32 lanes/node, uint2 (8 B) loads ----------------
template <int U>
__device__ __forceinline__ float4 gather32(const int* __restrict__ rowptr,
                                           const int2* __restrict__ emeta,
                                           const uint2* __restrict__ hin,
                                           int n, int lane) {
    float a0 = 0.f, a1 = 0.f, a2 = 0.f, a3 = 0.f;
    float b0 = 0.f, b1 = 0.f, b2 = 0.f, b3 = 0.f;
    int j = rowptr[n], j1 = rowptr[n + 1];
    for (; j + U - 1 < j1; j += U) {
        int2  m[U];
        uint2 u[U];
#pragma unroll
        for (int k = 0; k < U; ++k) m[k] = emeta[j + k];
#pragma unroll
        for (int k = 0; k < U; ++k) u[k] = hin[(size_t)m[k].x * 32 + lane];
#pragma unroll
        for (int k = 0; k < U; ++k) {
            float w = __int_as_float(m[k].y);
            float4 g = h4_to_f4(u[k]);
            if (k & 1) { b0 += w * g.x; b1 += w * g.y; b2 += w * g.z; b3 += w * g.w; }
            else       { a0 += w * g.x; a1 += w * g.y; a2 += w * g.z; a3 += w * g.w; }
        }
    }
    for (; j < j1; ++j) {
        int2 m = emeta[j];
        float w = __int_as_float(m.y);
        float4 g = h4_to_f4(hin[(size_t)m.x * 32 + lane]);
        a0 += w * g.x; a1 += w * g.y; a2 += w * g.z; a3 += w * g.w;
    }
    return make_float4(a0 + b0, a1 + b1, a2 + b2, a3 + b3);
}

// ---------------- LEAN hop: h_out = A * h_in (fp16) ----------------
__global__ __launch_bounds__(256) void k_hop(const int* __restrict__ rowptr,
                                             const int2* __restrict__ emeta,
                                             const uint2* __restrict__ hin,
                                             uint2* __restrict__ hout, int N) {
    int t = threadIdx.x;
    int nl = t >> 5, lane = t & 31;
    int n = blockIdx.x * 8 + nl;
    if (n >= N) return;
    float4 av = gather32<4>(rowptr, emeta, hin, n, lane);
    hout[(size_t)n * 32 + lane] = f4_to_h4(av);
}

// ---------------- MFMA combine: rows (n*4+b) x K=128 @ W(128x32) ----------------
// A: fp16 tables h0..h3, row-major [r][32]; fragment: row = lane&15,
// k = (lane>>4)*8 + j (contiguous 8 = one 16B load per table).
// B: W[k][o] fp16 fragments: col = lane&15, k = (lane>>4)*8 + j (built once from LDS).
// C/D (m89-verified, dtype-independent): col = lane&15, row = (lane>>4)*4 + reg.
// MODE 1: hout fp16 [r][32] (in-place over h0 safe: wave reads its tile before storing)
// MODE 2: out_h f32 [(b*N+n)][32] + pred[b*N+n]
template <int MODE>
__global__ __launch_bounds__(256) void k_comb_mfma(const f16* __restrict__ h0,
                                                   const f16* __restrict__ h1,
                                                   const f16* __restrict__ h2,
                                                   const f16* __restrict__ h3,
                                                   const float* __restrict__ W,
                                                   const float* __restrict__ bias,
                                                   f16* __restrict__ hout,
                                                   float* __restrict__ out_h,
                                                   const float* __restrict__ Wr,
                                                   const float* __restrict__ br,
                                                   float* __restrict__ pred, int N) {
    __shared__ float wsh[4096];          // (4,32,32) f32 W, 16 KB
    int t = threadIdx.x;
#pragma unroll
    for (int i = 0; i < 16; ++i) wsh[t + i * 256] = W[t + i * 256];
    __syncthreads();

    int lane = t & 63;
    int wid  = t >> 6;                   // wave 0..3
    int lrow = lane & 15;                // A-row within tile / C-col
    int kgrp = lane >> 4;                // 0..3

    // B fragments: bf[kk][oc][j] = W[kk*32 + kgrp*8 + j][oc*16 + lrow]
    f16x8 bf[4][2];
#pragma unroll
    for (int kk = 0; kk < 4; ++kk)
#pragma unroll
        for (int oc = 0; oc < 2; ++oc)
#pragma unroll
            for (int j = 0; j < 8; ++j)
                bf[kk][oc][j] = (f16)wsh[(kk * 32 + kgrp * 8 + j) * 32 + oc * 16 + lrow];

    float blo = bias[lrow], bhi = bias[16 + lrow];
    float wrlo = 0.f, wrhi = 0.f, br0 = 0.f;
    if (MODE == 2) { wrlo = Wr[lrow]; wrhi = Wr[16 + lrow]; br0 = br[0]; }

    int R = N * 4;
    int ntiles = (R + 15) >> 4;
    int nwaves = gridDim.x * 4;
    for (int tile = blockIdx.x * 4 + wid; tile < ntiles; tile += nwaves) {
        int arow = tile * 16 + lrow;
        if (arow >= R) arow = R - 1;             // tail clamp (loads only)
        size_t abase = (size_t)arow * 32 + kgrp * 8;
        f16x8 a0 = *(const f16x8*)(h0 + abase);
        f16x8 a1 = *(const f16x8*)(h1 + abase);
        f16x8 a2 = *(const f16x8*)(h2 + abase);
        f16x8 a3 = *(const f16x8*)(h3 + abase);

        f32x4 acc0 = {0.f, 0.f, 0.f, 0.f};
        f32x4 acc1 = {0.f, 0.f, 0.f, 0.f};
        acc0 = __builtin_amdgcn_mfma_f32_16x16x32_f16(a0, bf[0][0], acc0, 0, 0, 0);
        acc0 = __builtin_amdgcn_mfma_f32_16x16x32_f16(a1, bf[1][0], acc0, 0, 0, 0);
        acc0 = __builtin_amdgcn_mfma_f32_16x16x32_f16(a2, bf[2][0], acc0, 0, 0, 0);
        acc0 = __builtin_amdgcn_mfma_f32_16x16x32_f16(a3, bf[3][0], acc0, 0, 0, 0);
        acc1 = __builtin_amdgcn_mfma_f32_16x16x32_f16(a0, bf[0][1], acc1, 0, 0, 0);
        acc1 = __builtin_amdgcn_mfma_f32_16x16x32_f16(a1, bf[1][1], acc1, 0, 0, 0);
        acc1 = __builtin_amdgcn_mfma_f32_16x16x32_f16(a2, bf[2][1], acc1, 0, 0, 0);
        acc1 = __builtin_amdgcn_mfma_f32_16x16x32_f16(a3, bf[3][1], acc1, 0, 0, 0);

#pragma unroll
        for (int reg = 0; reg < 4; ++reg) {
            int orow = tile * 16 + kgrp * 4 + reg;
            float v0 = tanhf(acc0[reg] + blo);
            float v1 = tanhf(acc1[reg] + bhi);
            if (MODE == 1) {
                if (orow < R) {
                    hout[(size_t)orow * 32 + lrow]      = (f16)v0;
                    hout[(size_t)orow * 32 + 16 + lrow] = (f16)v1;
                }
            } else {
                float p = v0 * wrlo + v1 * wrhi;
                p += __shfl_xor(p, 1);
                p += __shfl_xor(p, 2);
                p += __shfl_xor(p, 4);
                p += __shfl_xor(p, 8);
                if (orow < R) {
                    int nn = orow >> 2, bb = orow & 3;
                    out_h[((size_t)bb * N + nn) * 32 + lrow]      = v0;
                    out_h[((size_t)bb * N + nn) * 32 + 16 + lrow] = v1;
                    if (lrow == 0) pred[(size_t)bb * N + nn] = p + br0;
                }
            }
        }
    }
}

// ---------------- driver ----------------

extern "C" void kernel_launch(void* const* d_in, const int* in_sizes, int n_in,
                              void* d_out, int out_size, void* d_ws, size_t ws_size,
                              hipStream_t stream) {
    const float* X  = (const float*)d_in[0];
    const int*   ei = (const int*)d_in[1];
    const float* W0 = (const float*)d_in[2];
    const float* b0 = (const float*)d_in[3];
    const float* W1 = (const float*)d_in[4];
    const float* b1 = (const float*)d_in[5];
    const float* W2 = (const float*)d_in[6];
    const float* b2 = (const float*)d_in[7];
    const float* Wr = (const float*)d_in[8];
    const float* br = (const float*)d_in[9];

    const int N = in_sizes[0] / 20;
    const int E = in_sizes[1] / 2;
    const int* src = ei;
    const int* dst = ei + E;
    const int nscan = (N + 1023) / 1024;

    char* ws = (char*)d_ws;
    size_t off = 0;
    auto take = [&](size_t bytes) -> char* {
        char* p = ws + off;
        off = (off + bytes + 255) & ~(size_t)255;
        return p;
    };
    const size_t HBYTES = (size_t)N * 128 * 2;   // fp16 node table (12.8 MB)
    const size_t GBYTES = (size_t)N * 20 * 4;    // layer-0 f32 table (4 MB)
    int*   deg    = (int*)  take((size_t)N * 4);
    int*   fill   = (int*)  take((size_t)N * 4);
    int*   rowptr = (int*)  take(((size_t)N + 1) * 4);
    float* dis    = (float*)take((size_t)N * 4);
    int*   bsum   = (int*)  take((size_t)(nscan + 1) * 4);
    int2*  emeta  = (int2*) take((size_t)E * 8);
    uint2* hA     = (uint2*)take(HBYTES);
    uint2* hB     = (uint2*)take(HBYTES);
    uint2* hC     = (uint2*)take(HBYTES);
    uint2* hD     = (uint2*)take(HBYTES);
    float* g0     = (float*)take(GBYTES);
    float* g1     = (float*)take(GBYTES);
    float* g2     = (float*)take(GBYTES);
    float* g3     = (float*)take(GBYTES);
    if (ws_size < off) return;

    dim3 wg(WG);
    auto nb = [](long long total) { return dim3((unsigned)((total + WG - 1) / WG)); };
    dim3 nb8((unsigned)((N + 7) / 8));     // hop: 8 nodes/block

    // ---- graph/normalization setup ----
    k_zero2<<<nb(N), wg, 0, stream>>>(deg, fill, N);
    k_count<<<nb(E), wg, 0, stream>>>(dst, deg, E);
    k_dis<<<nb(N), wg, 0, stream>>>(deg, dis, N);
    k_scan_blk<<<dim3(nscan), dim3(1024), 0, stream>>>(deg, rowptr, bsum, N);
    k_scan_top<<<dim3(1), dim3(64), 0, stream>>>(bsum, rowptr + N, nscan);
    k_scan_add<<<nb(N), wg, 0, stream>>>(rowptr, bsum, N);
    k_scatter<<<nb(E), wg, 0, stream>>>(src, dst, rowptr, fill, dis, emeta, E);

    // ---- h0 = X^T -> [n][w][4b] ----
    k_xpose<<<nb((long long)N * 20), wg, 0, stream>>>(X, g0, N);

    float* out_pred = (float*)d_out;
    float* out_h    = (float*)d_out + (size_t)4 * N;

    // ---- layer 0 (5 -> 32): 3 lean f32 hops + combine ----
    k_spmm20<<<nb((long long)N * 5), wg, 0, stream>>>(rowptr, emeta, g0, g1, N);
    k_spmm20<<<nb((long long)N * 5), wg, 0, stream>>>(rowptr, emeta, g1, g2, N);
    k_spmm20<<<nb((long long)N * 5), wg, 0, stream>>>(rowptr, emeta, g2, g3, N);
    k_comb20<<<nb((long long)N * 32), wg, 0, stream>>>(g0, g1, g2, g3, W0, b0, hA, N);

    // ---- layer 1 (32 -> 32): 3 lean hops + MFMA combine ----
    k_hop<<<nb8, wg, 0, stream>>>(rowptr, emeta, hA, hB, N);
    k_hop<<<nb8, wg, 0, stream>>>(rowptr, emeta, hB, hC, N);
    k_hop<<<nb8, wg, 0, stream>>>(rowptr, emeta, hC, hD, N);
    k_comb_mfma<1><<<dim3(1024), wg, 0, stream>>>((const f16*)hA, (const f16*)hB,
                                                  (const f16*)hC, (const f16*)hD,
                                                  W1, b1, (f16*)hA,
                                                  nullptr, nullptr, nullptr, nullptr, N);

    // ---- layer 2 (32 -> 32): 3 lean hops + MFMA combine(out) ----
    k_hop<<<nb8, wg, 0, stream>>>(rowptr, emeta, hA, hB, N);
    k_hop<<<nb8, wg, 0, stream>>>(rowptr, emeta, hB, hC, N);
    k_hop<<<nb8, wg, 0, stream>>>(rowptr, emeta, hC, hD, N);
    k_comb_mfma<2><<<dim3(1024), wg, 0, stream>>>((const f16*)hA, (const f16*)hB,
                                                  (const f16*)hC, (const f16*)hD,
                                                  W2, b2, nullptr,
                                                  out_h, Wr, br, out_pred, N);
}